// Round 17
// baseline (712.699 us; speedup 1.0000x reference)
//
#include <hip/hip_runtime.h>
#include <stdint.h>

#define BB 2
#define NQ 4096
#define NK 8192
#define DD 512
#define HH 4
#define TOPK 64

typedef unsigned int u32;
typedef unsigned long long u64;

#if defined(__has_builtin)
#if __has_builtin(__builtin_amdgcn_sdot4)
#define HAVE_SDOT4 1
#endif
#endif

__device__ __forceinline__ int dot4i8(u32 a, u32 b, int acc) {
#ifdef HAVE_SDOT4
    return __builtin_amdgcn_sdot4((int)a, (int)b, acc, false);
#else
    acc += (int)(signed char)(a & 0xFF) * (int)(signed char)(b & 0xFF);
    acc += (int)(signed char)((a >> 8) & 0xFF) * (int)(signed char)((b >> 8) & 0xFF);
    acc += (int)(signed char)((a >> 16) & 0xFF) * (int)(signed char)((b >> 16) & 0xFF);
    acc += (int)(signed char)((a >> 24) & 0xFF) * (int)(signed char)((b >> 24) & 0xFF);
    return acc;
#endif
}

// ---- GOLDEN accumulation order (verified bit-exact, round 13): 2-accumulator
// interleaved FMA chains (even/odd within each float4), one combining add.

#define PROJ_BODY(EMIT)                                                          \
    __shared__ float4 xs[16][128];                                               \
    __shared__ float4 wl[128][16];                                               \
    const int nqrows = BB * NQ;                                                  \
    int blk = blockIdx.x;                                                        \
    int half = blk & 1;                                                          \
    int row0 = (blk >> 1) << 4;                                                  \
    int type = (row0 >= nqrows);                                                 \
    int trow0 = type ? row0 - nqrows : row0;                                     \
    int b = type ? (trow0 >> 13) : (trow0 >> 12);                                \
    const float* X = type ? key : query;                                         \
    const float* W = type ? Wk : Wq;                                             \
    const int t = threadIdx.x;                                                   \
    {                                                                            \
        const float4* xg = (const float4*)(X + (size_t)trow0 * DD);              \
        float4* xsf = &xs[0][0];                                                 \
        for (int i = t; i < 2048; i += 256) xsf[i] = xg[i];                      \
        const float4* wg = (const float4*)W;                                     \
        for (int i = t; i < 2048; i += 256) {                                    \
            int oo = i & 15, jj = i >> 4;                                        \
            wl[jj][oo] = wg[(size_t)(half * 16 + oo) * 128 + jj];                \
        }                                                                        \
    }                                                                            \
    __syncthreads();                                                             \
    int o16 = t & 15, lr = t >> 4;                                               \
    int o = half * 16 + o16;                                                     \
    int h = o >> 3;                                                              \
    int trow = trow0 + lr;                                                       \
    float acc0 = 0.f, acc1 = 0.f;                                                \
    _Pragma("unroll 8")                                                          \
    for (int j = 0; j < 128; ++j) {                                              \
        float4 a = xs[lr][j];                                                    \
        float4 bb = wl[j][o16];                                                  \
        acc0 = fmaf(a.x, bb.x, acc0);                                            \
        acc1 = fmaf(a.y, bb.y, acc1);                                            \
        acc0 = fmaf(a.z, bb.z, acc0);                                            \
        acc1 = fmaf(a.w, bb.w, acc1);                                            \
    }                                                                            \
    float v = acc0 + acc1;                                                       \
    EMIT

__global__ __launch_bounds__(256, 2) void proj_absmax_kernel(
        const float* __restrict__ query, const float* __restrict__ key,
        const float* __restrict__ Wq, const float* __restrict__ Wk,
        u32* __restrict__ scale_bits) {
#pragma clang fp contract(off)
    __shared__ u32 lmax[4];
    if (threadIdx.x < 4) lmax[threadIdx.x] = 0u;
    PROJ_BODY(
        u32 bits = __float_as_uint(fabsf(v));
        __syncthreads();
        atomicMax(&lmax[h], bits);
        __syncthreads();
        if (threadIdx.x < 4 && lmax[threadIdx.x])
            atomicMax(&scale_bits[type * 8 + b * 4 + threadIdx.x], lmax[threadIdx.x]);
    )
}

__global__ __launch_bounds__(256, 2) void proj_quant_kernel(
        const float* __restrict__ query, const float* __restrict__ key,
        const float* __restrict__ Wq, const float* __restrict__ Wk,
        const u32* __restrict__ scale_bits,
        char* __restrict__ q8, char* __restrict__ kp8) {
#pragma clang fp contract(off)
    PROJ_BODY(
        float mx = __uint_as_float(scale_bits[type * 8 + b * 4 + h]);
        float scale = (mx + 1e-6f) / 127.0f;
        float r = rintf(v / scale);
        r = fminf(fmaxf(r, -127.f), 127.f);
        (type ? kp8 : q8)[(size_t)trow * 32 + o] = (char)(int)r;
    )
}

// 32-way repetition macro: named scalars (cannot be demoted to scratch).
#define R32(M) M(0) M(1) M(2) M(3) M(4) M(5) M(6) M(7) M(8) M(9) M(10) M(11) \
    M(12) M(13) M(14) M(15) M(16) M(17) M(18) M(19) M(20) M(21) M(22) M(23) \
    M(24) M(25) M(26) M(27) M(28) M(29) M(30) M(31)

// ---------------- fused scores + EXACT top-64, register-resident keys ----------------
__global__ __launch_bounds__(256, 4) void score_topk_kernel(
    const char* __restrict__ q8, const char* __restrict__ kp8,
    const u32* __restrict__ scale_bits, const float* __restrict__ w,
    int* __restrict__ out) {
#pragma clang fp contract(off)
    __shared__ u64 wmax[2][4];

    const int row = blockIdx.x;  // b*NQ + qi
    const int b = row >> 12;
    const int t = threadIdx.x;
    const int wv = t >> 6;

    const u32* qr = (const u32*)(q8 + (size_t)row * 32);
    u32 qa[8];
#pragma unroll
    for (int j = 0; j < 8; ++j) qa[j] = qr[j];

    float ts[HH], wt[HH];
#pragma unroll
    for (int h = 0; h < HH; ++h) {
        float qs = (__uint_as_float(scale_bits[b * 4 + h]) + 1e-6f) / 127.0f;
        float ks = (__uint_as_float(scale_bits[8 + b * 4 + h]) + 1e-6f) / 127.0f;
        ts[h] = qs * ks;
        wt[h] = w[h];
    }

    const u32* kbase = (const u32*)(kp8 + (size_t)b * NK * 32);

#define DECLK(i) u64 k##i;
    R32(DECLK)
#undef DECLK

#define BUILDK(i)                                                                \
    {                                                                            \
        int n = t + (i) * 256;                                                   \
        const u32* kr = kbase + (size_t)n * 8;                                   \
        uint4 c0 = *(const uint4*)(kr);                                          \
        uint4 c1 = *(const uint4*)(kr + 4);                                      \
        float acc = 0.f;                                                         \
        { int s = dot4i8(qa[0], c0.x, 0); s = dot4i8(qa[1], c0.y, s);            \
          float sf = (float)s * ts[0]; sf = fmaxf(sf, 0.f);                      \
          float pr = sf * wt[0]; acc = acc + pr; }                               \
        { int s = dot4i8(qa[2], c0.z, 0); s = dot4i8(qa[3], c0.w, s);            \
          float sf = (float)s * ts[1]; sf = fmaxf(sf, 0.f);                      \
          float pr = sf * wt[1]; acc = acc + pr; }                               \
        { int s = dot4i8(qa[4], c1.x, 0); s = dot4i8(qa[5], c1.y, s);            \
          float sf = (float)s * ts[2]; sf = fmaxf(sf, 0.f);                      \
          float pr = sf * wt[2]; acc = acc + pr; }                               \
        { int s = dot4i8(qa[6], c1.z, 0); s = dot4i8(qa[7], c1.w, s);            \
          float sf = (float)s * ts[3]; sf = fmaxf(sf, 0.f);                      \
          float pr = sf * wt[3]; acc = acc + pr; }                               \
        acc = acc + 0.0f;                                                        \
        u32 u = __float_as_uint(acc);                                            \
        u = (u & 0x80000000u) ? ~u : (u | 0x80000000u);                          \
        k##i = ((u64)u << 32) | (u64)(0xFFFFFFFFu - (u32)n);                     \
    }
    R32(BUILDK)
#undef BUILDK

    u64 lmax = k0;
#define MAXK(i) lmax = k##i > lmax ? k##i : lmax;
    R32(MAXK)

    for (int r = 0; r < TOPK; ++r) {
        u64 m = lmax;
#pragma unroll
        for (int off = 32; off > 0; off >>= 1) {
            u64 o = __shfl_down(m, off, 64);
            m = o > m ? o : m;
        }
        int p = r & 1;
        if ((t & 63) == 0) wmax[p][wv] = m;
        __syncthreads();
        u64 g0 = wmax[p][0] > wmax[p][1] ? wmax[p][0] : wmax[p][1];
        u64 g1 = wmax[p][2] > wmax[p][3] ? wmax[p][2] : wmax[p][3];
        u64 gm = g0 > g1 ? g0 : g1;
        u32 n = 0xFFFFFFFFu - (u32)gm;
        if (t == 0) out[(size_t)row * TOPK + r] = (int)n;
        if ((int)(n & 255u) == t) {  // owner: clear winner (selects), refresh max
            int slot = (int)(n >> 8);
#define CLRK(i) k##i = (slot == (i)) ? 0ull : k##i;
            R32(CLRK)
#undef CLRK
            lmax = k0;
            R32(MAXK)
        }
        // no trailing barrier: next round uses the other wmax buffer
    }
#undef MAXK
}

extern "C" void kernel_launch(void* const* d_in, const int* in_sizes, int n_in,
                              void* d_out, int out_size, void* d_ws, size_t ws_size,
                              hipStream_t stream) {
    const float* query = (const float*)d_in[0];
    const float* key = (const float*)d_in[1];
    const float* Wq = (const float*)d_in[2];
    const float* Wk = (const float*)d_in[3];
    const float* ow = (const float*)d_in[4];

    char* ws = (char*)d_ws;
    u32* scale_bits = (u32*)ws;
    char* q8 = ws + 1024;
    char* kp8 = q8 + BB * NQ * 32;
    int* out = (int*)d_out;

    hipMemsetAsync(scale_bits, 0, 64, stream);

    const int nblocks = (BB * (NQ + NK)) / 16 * 2;  // 3072
    proj_absmax_kernel<<<nblocks, 256, 0, stream>>>(query, key, Wq, Wk, scale_bits);
    proj_quant_kernel<<<nblocks, 256, 0, stream>>>(query, key, Wq, Wk, scale_bits, q8, kp8);
    score_topk_kernel<<<BB * NQ, 256, 0, stream>>>(q8, kp8, scale_bits, ow, out);
}

// Round 18
// 712.344 us; speedup vs baseline: 1.0005x; 1.0005x over previous
//
#include <hip/hip_runtime.h>
#include <stdint.h>

#define BB 2
#define NQ 4096
#define NK 8192
#define DD 512
#define HH 4
#define TOPK 64

typedef unsigned int u32;
typedef unsigned long long u64;

#if defined(__has_builtin)
#if __has_builtin(__builtin_amdgcn_sdot4)
#define HAVE_SDOT4 1
#endif
#endif

__device__ __forceinline__ int dot4i8(u32 a, u32 b, int acc) {
#ifdef HAVE_SDOT4
    return __builtin_amdgcn_sdot4((int)a, (int)b, acc, false);
#else
    acc += (int)(signed char)(a & 0xFF) * (int)(signed char)(b & 0xFF);
    acc += (int)(signed char)((a >> 8) & 0xFF) * (int)(signed char)((b >> 8) & 0xFF);
    acc += (int)(signed char)((a >> 16) & 0xFF) * (int)(signed char)((b >> 16) & 0xFF);
    acc += (int)(signed char)((a >> 24) & 0xFF) * (int)(signed char)((b >> 24) & 0xFF);
    return acc;
#endif
}

// ---- GOLDEN accumulation order (verified bit-exact, round 13): 2-accumulator
// interleaved FMA chains (even/odd within each float4), one combining add.

#define PROJ_BODY(EMIT)                                                          \
    __shared__ float4 xs[16][128];                                               \
    __shared__ float4 wl[128][16];                                               \
    const int nqrows = BB * NQ;                                                  \
    int blk = blockIdx.x;                                                        \
    int half = blk & 1;                                                          \
    int row0 = (blk >> 1) << 4;                                                  \
    int type = (row0 >= nqrows);                                                 \
    int trow0 = type ? row0 - nqrows : row0;                                     \
    int b = type ? (trow0 >> 13) : (trow0 >> 12);                                \
    const float* X = type ? key : query;                                         \
    const float* W = type ? Wk : Wq;                                             \
    const int t = threadIdx.x;                                                   \
    {                                                                            \
        const float4* xg = (const float4*)(X + (size_t)trow0 * DD);              \
        float4* xsf = &xs[0][0];                                                 \
        for (int i = t; i < 2048; i += 256) xsf[i] = xg[i];                      \
        const float4* wg = (const float4*)W;                                     \
        for (int i = t; i < 2048; i += 256) {                                    \
            int oo = i & 15, jj = i >> 4;                                        \
            wl[jj][oo] = wg[(size_t)(half * 16 + oo) * 128 + jj];                \
        }                                                                        \
    }                                                                            \
    __syncthreads();                                                             \
    int o16 = t & 15, lr = t >> 4;                                               \
    int o = half * 16 + o16;                                                     \
    int h = o >> 3;                                                              \
    int trow = trow0 + lr;                                                       \
    float acc0 = 0.f, acc1 = 0.f;                                                \
    _Pragma("unroll 8")                                                          \
    for (int j = 0; j < 128; ++j) {                                              \
        float4 a = xs[lr][j];                                                    \
        float4 bb = wl[j][o16];                                                  \
        acc0 = fmaf(a.x, bb.x, acc0);                                            \
        acc1 = fmaf(a.y, bb.y, acc1);                                            \
        acc0 = fmaf(a.z, bb.z, acc0);                                            \
        acc1 = fmaf(a.w, bb.w, acc1);                                            \
    }                                                                            \
    float v = acc0 + acc1;                                                       \
    EMIT

__global__ __launch_bounds__(256, 2) void proj_absmax_kernel(
        const float* __restrict__ query, const float* __restrict__ key,
        const float* __restrict__ Wq, const float* __restrict__ Wk,
        u32* __restrict__ scale_bits) {
#pragma clang fp contract(off)
    __shared__ u32 lmax[4];
    if (threadIdx.x < 4) lmax[threadIdx.x] = 0u;
    PROJ_BODY(
        u32 bits = __float_as_uint(fabsf(v));
        __syncthreads();
        atomicMax(&lmax[h], bits);
        __syncthreads();
        if (threadIdx.x < 4 && lmax[threadIdx.x])
            atomicMax(&scale_bits[type * 8 + b * 4 + threadIdx.x], lmax[threadIdx.x]);
    )
}

__global__ __launch_bounds__(256, 2) void proj_quant_kernel(
        const float* __restrict__ query, const float* __restrict__ key,
        const float* __restrict__ Wq, const float* __restrict__ Wk,
        const u32* __restrict__ scale_bits,
        char* __restrict__ q8, char* __restrict__ kp8) {
#pragma clang fp contract(off)
    PROJ_BODY(
        float mx = __uint_as_float(scale_bits[type * 8 + b * 4 + h]);
        float scale = (mx + 1e-6f) / 127.0f;
        float r = rintf(v / scale);
        r = fminf(fmaxf(r, -127.f), 127.f);
        (type ? kp8 : q8)[(size_t)trow * 32 + o] = (char)(int)r;
    )
}

// 32-way repetition macro: named scalars, statically indexed everywhere.
#define R32(M) M(0) M(1) M(2) M(3) M(4) M(5) M(6) M(7) M(8) M(9) M(10) M(11) \
    M(12) M(13) M(14) M(15) M(16) M(17) M(18) M(19) M(20) M(21) M(22) M(23) \
    M(24) M(25) M(26) M(27) M(28) M(29) M(30) M(31)

// ---------------- fused scores + EXACT top-64, register-resident keys ----------------
// amdgpu_waves_per_eu(4,4): pin occupancy target to 4 waves/EU -> RA budget
// 512/4 = 128 VGPR. Without the MAX bound the RA targets 10 waves/EU (52 VGPR)
// and spills the 64-VGPR key set to scratch (rounds 14-17 evidence).
__global__ __attribute__((amdgpu_waves_per_eu(4, 4))) __launch_bounds__(256)
void score_topk_kernel(
    const char* __restrict__ q8, const char* __restrict__ kp8,
    const u32* __restrict__ scale_bits, const float* __restrict__ w,
    int* __restrict__ out) {
#pragma clang fp contract(off)
    __shared__ u64 wmax[2][4];

    const int row = blockIdx.x;  // b*NQ + qi
    const int b = row >> 12;
    const int t = threadIdx.x;
    const int wv = t >> 6;

    const u32* qr = (const u32*)(q8 + (size_t)row * 32);
    u32 qa[8];
#pragma unroll
    for (int j = 0; j < 8; ++j) qa[j] = qr[j];

    float ts[HH], wt[HH];
#pragma unroll
    for (int h = 0; h < HH; ++h) {
        float qs = (__uint_as_float(scale_bits[b * 4 + h]) + 1e-6f) / 127.0f;
        float ks = (__uint_as_float(scale_bits[8 + b * 4 + h]) + 1e-6f) / 127.0f;
        ts[h] = qs * ks;
        wt[h] = w[h];
    }

    const u32* kbase = (const u32*)(kp8 + (size_t)b * NK * 32);

#define DECLK(i) u64 k##i;
    R32(DECLK)
#undef DECLK

#define BUILDK(i)                                                                \
    {                                                                            \
        int n = t + (i) * 256;                                                   \
        const u32* kr = kbase + (size_t)n * 8;                                   \
        uint4 c0 = *(const uint4*)(kr);                                          \
        uint4 c1 = *(const uint4*)(kr + 4);                                      \
        float acc = 0.f;                                                         \
        { int s = dot4i8(qa[0], c0.x, 0); s = dot4i8(qa[1], c0.y, s);            \
          float sf = (float)s * ts[0]; sf = fmaxf(sf, 0.f);                      \
          float pr = sf * wt[0]; acc = acc + pr; }                               \
        { int s = dot4i8(qa[2], c0.z, 0); s = dot4i8(qa[3], c0.w, s);            \
          float sf = (float)s * ts[1]; sf = fmaxf(sf, 0.f);                      \
          float pr = sf * wt[1]; acc = acc + pr; }                               \
        { int s = dot4i8(qa[4], c1.x, 0); s = dot4i8(qa[5], c1.y, s);            \
          float sf = (float)s * ts[2]; sf = fmaxf(sf, 0.f);                      \
          float pr = sf * wt[2]; acc = acc + pr; }                               \
        { int s = dot4i8(qa[6], c1.z, 0); s = dot4i8(qa[7], c1.w, s);            \
          float sf = (float)s * ts[3]; sf = fmaxf(sf, 0.f);                      \
          float pr = sf * wt[3]; acc = acc + pr; }                               \
        acc = acc + 0.0f;                                                        \
        u32 u = __float_as_uint(acc);                                            \
        u = (u & 0x80000000u) ? ~u : (u | 0x80000000u);                          \
        k##i = ((u64)u << 32) | (u64)(0xFFFFFFFFu - (u32)n);                     \
    }
    R32(BUILDK)
#undef BUILDK

    u64 lmax = k0;
#define MAXK(i) lmax = k##i > lmax ? k##i : lmax;
    R32(MAXK)

    for (int r = 0; r < TOPK; ++r) {
        u64 m = lmax;
#pragma unroll
        for (int off = 32; off > 0; off >>= 1) {
            u64 o = __shfl_down(m, off, 64);
            m = o > m ? o : m;
        }
        int p = r & 1;
        if ((t & 63) == 0) wmax[p][wv] = m;
        __syncthreads();
        u64 g0 = wmax[p][0] > wmax[p][1] ? wmax[p][0] : wmax[p][1];
        u64 g1 = wmax[p][2] > wmax[p][3] ? wmax[p][2] : wmax[p][3];
        u64 gm = g0 > g1 ? g0 : g1;
        u32 n = 0xFFFFFFFFu - (u32)gm;
        if (t == 0) out[(size_t)row * TOPK + r] = (int)n;
        if ((int)(n & 255u) == t) {  // owner: clear winner (selects), refresh max
            int slot = (int)(n >> 8);
#define CLRK(i) k##i = (slot == (i)) ? 0ull : k##i;
            R32(CLRK)
#undef CLRK
            lmax = k0;
            R32(MAXK)
        }
        // no trailing barrier: next round uses the other wmax buffer
    }
#undef MAXK
}

extern "C" void kernel_launch(void* const* d_in, const int* in_sizes, int n_in,
                              void* d_out, int out_size, void* d_ws, size_t ws_size,
                              hipStream_t stream) {
    const float* query = (const float*)d_in[0];
    const float* key = (const float*)d_in[1];
    const float* Wq = (const float*)d_in[2];
    const float* Wk = (const float*)d_in[3];
    const float* ow = (const float*)d_in[4];

    char* ws = (char*)d_ws;
    u32* scale_bits = (u32*)ws;
    char* q8 = ws + 1024;
    char* kp8 = q8 + BB * NQ * 32;
    int* out = (int*)d_out;

    hipMemsetAsync(scale_bits, 0, 64, stream);

    const int nblocks = (BB * (NQ + NK)) / 16 * 2;  // 3072
    proj_absmax_kernel<<<nblocks, 256, 0, stream>>>(query, key, Wq, Wk, scale_bits);
    proj_quant_kernel<<<nblocks, 256, 0, stream>>>(query, key, Wq, Wk, scale_bits, q8, kp8);
    score_topk_kernel<<<BB * NQ, 256, 0, stream>>>(q8, kp8, scale_bits, ow, out);
}

// Round 19
// 632.212 us; speedup vs baseline: 1.1273x; 1.1267x over previous
//
#include <hip/hip_runtime.h>
#include <stdint.h>

#define BB 2
#define NQ 4096
#define NK 8192
#define DD 512
#define HH 4
#define TOPK 64
#define CAP 512

typedef unsigned int u32;
typedef unsigned long long u64;

#if defined(__has_builtin)
#if __has_builtin(__builtin_amdgcn_sdot4)
#define HAVE_SDOT4 1
#endif
#endif

__device__ __forceinline__ int dot4i8(u32 a, u32 b, int acc) {
#ifdef HAVE_SDOT4
    return __builtin_amdgcn_sdot4((int)a, (int)b, acc, false);
#else
    acc += (int)(signed char)(a & 0xFF) * (int)(signed char)(b & 0xFF);
    acc += (int)(signed char)((a >> 8) & 0xFF) * (int)(signed char)((b >> 8) & 0xFF);
    acc += (int)(signed char)((a >> 16) & 0xFF) * (int)(signed char)((b >> 16) & 0xFF);
    acc += (int)(signed char)((a >> 24) & 0xFF) * (int)(signed char)((b >> 24) & 0xFF);
    return acc;
#endif
}

// ---- GOLDEN accumulation order (verified bit-exact, round 13): 2-accumulator
// interleaved FMA chains (even/odd within each float4), one combining add.

#define PROJ_BODY(EMIT)                                                          \
    __shared__ float4 xs[16][128];                                               \
    __shared__ float4 wl[128][16];                                               \
    const int nqrows = BB * NQ;                                                  \
    int blk = blockIdx.x;                                                        \
    int half = blk & 1;                                                          \
    int row0 = (blk >> 1) << 4;                                                  \
    int type = (row0 >= nqrows);                                                 \
    int trow0 = type ? row0 - nqrows : row0;                                     \
    int b = type ? (trow0 >> 13) : (trow0 >> 12);                                \
    const float* X = type ? key : query;                                         \
    const float* W = type ? Wk : Wq;                                             \
    const int t = threadIdx.x;                                                   \
    {                                                                            \
        const float4* xg = (const float4*)(X + (size_t)trow0 * DD);              \
        float4* xsf = &xs[0][0];                                                 \
        for (int i = t; i < 2048; i += 256) xsf[i] = xg[i];                      \
        const float4* wg = (const float4*)W;                                     \
        for (int i = t; i < 2048; i += 256) {                                    \
            int oo = i & 15, jj = i >> 4;                                        \
            wl[jj][oo] = wg[(size_t)(half * 16 + oo) * 128 + jj];                \
        }                                                                        \
    }                                                                            \
    __syncthreads();                                                             \
    int o16 = t & 15, lr = t >> 4;                                               \
    int o = half * 16 + o16;                                                     \
    int h = o >> 3;                                                              \
    int trow = trow0 + lr;                                                       \
    float acc0 = 0.f, acc1 = 0.f;                                                \
    _Pragma("unroll 8")                                                          \
    for (int j = 0; j < 128; ++j) {                                              \
        float4 a = xs[lr][j];                                                    \
        float4 bb = wl[j][o16];                                                  \
        acc0 = fmaf(a.x, bb.x, acc0);                                            \
        acc1 = fmaf(a.y, bb.y, acc1);                                            \
        acc0 = fmaf(a.z, bb.z, acc0);                                            \
        acc1 = fmaf(a.w, bb.w, acc1);                                            \
    }                                                                            \
    float v = acc0 + acc1;                                                       \
    EMIT

__global__ __launch_bounds__(256, 2) void proj_absmax_kernel(
        const float* __restrict__ query, const float* __restrict__ key,
        const float* __restrict__ Wq, const float* __restrict__ Wk,
        u32* __restrict__ scale_bits) {
#pragma clang fp contract(off)
    __shared__ u32 lmax[4];
    if (threadIdx.x < 4) lmax[threadIdx.x] = 0u;
    PROJ_BODY(
        u32 bits = __float_as_uint(fabsf(v));
        __syncthreads();
        atomicMax(&lmax[h], bits);
        __syncthreads();
        if (threadIdx.x < 4 && lmax[threadIdx.x])
            atomicMax(&scale_bits[type * 8 + b * 4 + threadIdx.x], lmax[threadIdx.x]);
    )
}

__global__ __launch_bounds__(256, 2) void proj_quant_kernel(
        const float* __restrict__ query, const float* __restrict__ key,
        const float* __restrict__ Wq, const float* __restrict__ Wk,
        const u32* __restrict__ scale_bits,
        char* __restrict__ q8, char* __restrict__ kp8) {
#pragma clang fp contract(off)
    PROJ_BODY(
        float mx = __uint_as_float(scale_bits[type * 8 + b * 4 + h]);
        float scale = (mx + 1e-6f) / 127.0f;
        float r = rintf(v / scale);
        r = fminf(fmaxf(r, -127.f), 127.f);
        (type ? kp8 : q8)[(size_t)trow * 32 + o] = (char)(int)r;
    )
}

// ---------------- fused scores + EXACT top-64 via radix-select + bitonic ----------------
// Keys (monotone f32 score bits || ~index) are distinct -> radix narrows to
// cc <= 64 at worst by shift=0; typical exit after 2-3 byte passes.
__global__ __launch_bounds__(256) void score_topk_kernel(
    const char* __restrict__ q8, const char* __restrict__ kp8,
    const u32* __restrict__ scale_bits, const float* __restrict__ w,
    int* __restrict__ out) {
#pragma clang fp contract(off)
    __shared__ u64 keys[NK];       // 64 KB
    __shared__ u32 hist[4][256];   // 4 KB
    __shared__ u64 cand[CAP];      // 4 KB
    __shared__ u64 sh_T;
    __shared__ u32 sh_G, sh_cc, sh_cnt;

    const int row = blockIdx.x;  // b*NQ + qi
    const int b = row >> 12;
    const int t = threadIdx.x;
    const int wv = t >> 6;

    const u32* qr = (const u32*)(q8 + (size_t)row * 32);
    u32 qa[8];
#pragma unroll
    for (int j = 0; j < 8; ++j) qa[j] = qr[j];

    float ts[HH], wt[HH];
#pragma unroll
    for (int h = 0; h < HH; ++h) {
        float qs = (__uint_as_float(scale_bits[b * 4 + h]) + 1e-6f) / 127.0f;
        float ks = (__uint_as_float(scale_bits[8 + b * 4 + h]) + 1e-6f) / 127.0f;
        ts[h] = qs * ks;
        wt[h] = w[h];
    }

    const u32* kbase = (const u32*)(kp8 + (size_t)b * NK * 32);
#pragma unroll 4
    for (int i = 0; i < 32; ++i) {
        int n = t + i * 256;
        const u32* kr = kbase + (size_t)n * 8;
        uint4 c0 = *(const uint4*)(kr);
        uint4 c1 = *(const uint4*)(kr + 4);
        float acc = 0.f;
        { int s = dot4i8(qa[0], c0.x, 0); s = dot4i8(qa[1], c0.y, s);
          float sf = (float)s * ts[0]; sf = fmaxf(sf, 0.f);
          float pr = sf * wt[0]; acc = acc + pr; }
        { int s = dot4i8(qa[2], c0.z, 0); s = dot4i8(qa[3], c0.w, s);
          float sf = (float)s * ts[1]; sf = fmaxf(sf, 0.f);
          float pr = sf * wt[1]; acc = acc + pr; }
        { int s = dot4i8(qa[4], c1.x, 0); s = dot4i8(qa[5], c1.y, s);
          float sf = (float)s * ts[2]; sf = fmaxf(sf, 0.f);
          float pr = sf * wt[2]; acc = acc + pr; }
        { int s = dot4i8(qa[6], c1.z, 0); s = dot4i8(qa[7], c1.w, s);
          float sf = (float)s * ts[3]; sf = fmaxf(sf, 0.f);
          float pr = sf * wt[3]; acc = acc + pr; }
        acc = acc + 0.0f;  // canonicalize -0 -> +0
        u32 u = __float_as_uint(acc);
        u = (u & 0x80000000u) ? ~u : (u | 0x80000000u);  // monotonic map
        keys[n] = ((u64)u << 32) | (u64)(0xFFFFFFFFu - (u32)n);  // ties: LOWER index wins
    }
    if (t == 0) { sh_T = 0ull; sh_G = 0u; }
    __syncthreads();

    // byte-wise radix from the top: narrow until candidates fit in CAP
    u32 cc = 0;
    for (int shift = 56; shift >= 0; shift -= 8) {
        for (int j = t; j < 1024; j += 256) ((u32*)hist)[j] = 0u;
        __syncthreads();
        u64 himask = (shift == 56) ? 0ull : (~0ull << (shift + 8));
        u64 hiT = sh_T & himask;
#pragma unroll 4
        for (int i = 0; i < 32; ++i) {
            u64 kk = keys[t + i * 256];
            if ((kk & himask) == hiT)
                atomicAdd(&hist[wv][(u32)(kk >> shift) & 0xFF], 1u);
        }
        __syncthreads();
        if (t == 0) {
            u32 running = sh_G;
            int bsel = 255;
            u32 binc = 0;
            for (; bsel >= 0; --bsel) {
                binc = hist[0][bsel] + hist[1][bsel] + hist[2][bsel] + hist[3][bsel];
                if (running + binc >= TOPK) break;
                running += binc;
            }
            sh_G = running;                               // count strictly above bin
            sh_T = hiT | ((u64)(u32)bsel << shift);       // refined threshold prefix
            sh_cc = running + binc;                       // count(keys >= prefix)
            sh_cnt = 0u;
        }
        __syncthreads();
        cc = sh_cc;
        if (cc <= CAP) break;
    }

    // gather candidates (cc of them, 64 <= cc <= CAP)
    u64 Tlow = sh_T;
#pragma unroll 4
    for (int i = 0; i < 32; ++i) {
        u64 kk = keys[t + i * 256];
        if (kk >= Tlow) {
            u32 p = atomicAdd(&sh_cnt, 1u);
            if (p < CAP) cand[p] = kk;
        }
    }
    __syncthreads();
    u32 cnt = sh_cnt;
    u32 P = 64;
    while (P < cnt) P <<= 1;  // pow2 size >= cnt, <= 512
    for (u32 j = cnt + t; j < P; j += 256) cand[j] = 0ull;

    // bitonic sort P elements descending
    for (u32 k2 = 2; k2 <= P; k2 <<= 1) {
        for (u32 j = k2 >> 1; j > 0; j >>= 1) {
            __syncthreads();
            for (u32 idx = t; idx < P; idx += 256) {
                u32 partner = idx ^ j;
                if (partner > idx) {
                    u64 a = cand[idx], c = cand[partner];
                    bool descBlock = ((idx & k2) == 0);
                    bool doswap = descBlock ? (a < c) : (a > c);
                    if (doswap) { cand[idx] = c; cand[partner] = a; }
                }
            }
        }
    }
    __syncthreads();

    if (t < TOPK)
        out[(size_t)row * TOPK + t] = (int)(0xFFFFFFFFu - (u32)cand[t]);
}

extern "C" void kernel_launch(void* const* d_in, const int* in_sizes, int n_in,
                              void* d_out, int out_size, void* d_ws, size_t ws_size,
                              hipStream_t stream) {
    const float* query = (const float*)d_in[0];
    const float* key = (const float*)d_in[1];
    const float* Wq = (const float*)d_in[2];
    const float* Wk = (const float*)d_in[3];
    const float* ow = (const float*)d_in[4];

    char* ws = (char*)d_ws;
    u32* scale_bits = (u32*)ws;
    char* q8 = ws + 1024;
    char* kp8 = q8 + BB * NQ * 32;
    int* out = (int*)d_out;

    (void)hipMemsetAsync(scale_bits, 0, 64, stream);

    const int nblocks = (BB * (NQ + NK)) / 16 * 2;  // 3072
    proj_absmax_kernel<<<nblocks, 256, 0, stream>>>(query, key, Wq, Wk, scale_bits);
    proj_quant_kernel<<<nblocks, 256, 0, stream>>>(query, key, Wq, Wk, scale_bits, q8, kp8);
    score_topk_kernel<<<BB * NQ, 256, 0, stream>>>(q8, kp8, scale_bits, ow, out);
}

// Round 20
// 384.233 us; speedup vs baseline: 1.8549x; 1.6454x over previous
//
#include <hip/hip_runtime.h>
#include <stdint.h>

#define BB 2
#define NQ 4096
#define NK 8192
#define DD 512
#define HH 4
#define TOPK 64
#define CAP 512
#define RPB 4        // rows per score block
#define HPAD 1088    // 1024 bins + bin>>4 padding

typedef unsigned int u32;
typedef unsigned long long u64;

#if defined(__has_builtin)
#if __has_builtin(__builtin_amdgcn_sdot4)
#define HAVE_SDOT4 1
#endif
#endif

__device__ __forceinline__ int dot4i8(u32 a, u32 b, int acc) {
#ifdef HAVE_SDOT4
    return __builtin_amdgcn_sdot4((int)a, (int)b, acc, false);
#else
    acc += (int)(signed char)(a & 0xFF) * (int)(signed char)(b & 0xFF);
    acc += (int)(signed char)((a >> 8) & 0xFF) * (int)(signed char)((b >> 8) & 0xFF);
    acc += (int)(signed char)((a >> 16) & 0xFF) * (int)(signed char)((b >> 16) & 0xFF);
    acc += (int)(signed char)((a >> 24) & 0xFF) * (int)(signed char)((b >> 24) & 0xFF);
    return acc;
#endif
}

// ---- GOLDEN accumulation order (verified bit-exact, round 13): 2-accumulator
// interleaved FMA chains (even/odd within each float4), one combining add.

#define PROJ_BODY(EMIT)                                                          \
    __shared__ float4 xs[16][128];                                               \
    __shared__ float4 wl[128][16];                                               \
    const int nqrows = BB * NQ;                                                  \
    int blk = blockIdx.x;                                                        \
    int half = blk & 1;                                                          \
    int row0 = (blk >> 1) << 4;                                                  \
    int type = (row0 >= nqrows);                                                 \
    int trow0 = type ? row0 - nqrows : row0;                                     \
    int b = type ? (trow0 >> 13) : (trow0 >> 12);                                \
    const float* X = type ? key : query;                                         \
    const float* W = type ? Wk : Wq;                                             \
    const int t = threadIdx.x;                                                   \
    {                                                                            \
        const float4* xg = (const float4*)(X + (size_t)trow0 * DD);              \
        float4* xsf = &xs[0][0];                                                 \
        for (int i = t; i < 2048; i += 256) xsf[i] = xg[i];                      \
        const float4* wg = (const float4*)W;                                     \
        for (int i = t; i < 2048; i += 256) {                                    \
            int oo = i & 15, jj = i >> 4;                                        \
            wl[jj][oo] = wg[(size_t)(half * 16 + oo) * 128 + jj];                \
        }                                                                        \
    }                                                                            \
    __syncthreads();                                                             \
    int o16 = t & 15, lr = t >> 4;                                               \
    int o = half * 16 + o16;                                                     \
    int h = o >> 3;                                                              \
    int trow = trow0 + lr;                                                       \
    float acc0 = 0.f, acc1 = 0.f;                                                \
    _Pragma("unroll 8")                                                          \
    for (int j = 0; j < 128; ++j) {                                              \
        float4 a = xs[lr][j];                                                    \
        float4 bb = wl[j][o16];                                                  \
        acc0 = fmaf(a.x, bb.x, acc0);                                            \
        acc1 = fmaf(a.y, bb.y, acc1);                                            \
        acc0 = fmaf(a.z, bb.z, acc0);                                            \
        acc1 = fmaf(a.w, bb.w, acc1);                                            \
    }                                                                            \
    float v = acc0 + acc1;                                                       \
    EMIT

__global__ __launch_bounds__(256, 2) void proj_absmax_kernel(
        const float* __restrict__ query, const float* __restrict__ key,
        const float* __restrict__ Wq, const float* __restrict__ Wk,
        u32* __restrict__ scale_bits) {
#pragma clang fp contract(off)
    __shared__ u32 lmax[4];
    if (threadIdx.x < 4) lmax[threadIdx.x] = 0u;
    PROJ_BODY(
        u32 bits = __float_as_uint(fabsf(v));
        __syncthreads();
        atomicMax(&lmax[h], bits);
        __syncthreads();
        if (threadIdx.x < 4 && lmax[threadIdx.x])
            atomicMax(&scale_bits[type * 8 + b * 4 + threadIdx.x], lmax[threadIdx.x]);
    )
}

__global__ __launch_bounds__(256, 2) void proj_quant_kernel(
        const float* __restrict__ query, const float* __restrict__ key,
        const float* __restrict__ Wq, const float* __restrict__ Wk,
        const u32* __restrict__ scale_bits,
        char* __restrict__ q8, char* __restrict__ kp8) {
#pragma clang fp contract(off)
    PROJ_BODY(
        float mx = __uint_as_float(scale_bits[type * 8 + b * 4 + h]);
        float scale = (mx + 1e-6f) / 127.0f;
        float r = rintf(v / scale);
        r = fminf(fmaxf(r, -127.f), 127.f);
        (type ? kp8 : q8)[(size_t)trow * 32 + o] = (char)(int)r;
    )
}

// mapped monotone score bits for row r from chunk regs c0,c1 (exact epilogue)
#define SCORE_U(r, udst) { \
    float acc = 0.f; \
    { int s = dot4i8(qs_l[r][0], c0.x, 0); s = dot4i8(qs_l[r][1], c0.y, s); \
      float sf = (float)s * ts_l[r][0]; sf = fmaxf(sf, 0.f); \
      float pr = sf * wt_l[0]; acc = acc + pr; } \
    { int s = dot4i8(qs_l[r][2], c0.z, 0); s = dot4i8(qs_l[r][3], c0.w, s); \
      float sf = (float)s * ts_l[r][1]; sf = fmaxf(sf, 0.f); \
      float pr = sf * wt_l[1]; acc = acc + pr; } \
    { int s = dot4i8(qs_l[r][4], c1.x, 0); s = dot4i8(qs_l[r][5], c1.y, s); \
      float sf = (float)s * ts_l[r][2]; sf = fmaxf(sf, 0.f); \
      float pr = sf * wt_l[2]; acc = acc + pr; } \
    { int s = dot4i8(qs_l[r][6], c1.z, 0); s = dot4i8(qs_l[r][7], c1.w, s); \
      float sf = (float)s * ts_l[r][3]; sf = fmaxf(sf, 0.f); \
      float pr = sf * wt_l[3]; acc = acc + pr; } \
    acc = acc + 0.0f; \
    u32 uu = __float_as_uint(acc); \
    udst = (uu & 0x80000000u) ? ~uu : (uu | 0x80000000u); }

// wave-local threshold selection over a filled histogram (run by wave wv==r)
#define SELECT_PASS(r, SHIFT, BINSN) do { \
    const int bpl_ = ((BINSN) >= 64) ? ((BINSN) / 64) : 1; \
    const int nact_ = ((BINSN) >= 64) ? 64 : (BINSN); \
    u32 P_ = 0u; \
    if (lane < nact_) { \
        for (int j_ = 0; j_ < bpl_; ++j_) { int bin_ = lane * bpl_ + j_; P_ += hist[r][bin_ + (bin_ >> 4)]; } } \
    u32 sI_ = P_; \
    for (int s_ = 1; s_ < 64; s_ <<= 1) { u32 o_ = __shfl_down(sI_, s_, 64); if (lane + s_ < 64) sI_ += o_; } \
    u32 sE_ = sI_ - P_; \
    u32 Gp_ = G_l[r]; \
    if (Gp_ + sE_ < TOPK && Gp_ + sI_ >= TOPK) { \
        u32 run_ = Gp_ + sE_; \
        for (int j_ = bpl_ - 1; j_ >= 0; --j_) { \
            int bin_ = lane * bpl_ + j_; u32 c_ = hist[r][bin_ + (bin_ >> 4)]; \
            if (run_ + c_ >= TOPK) { \
                T_l[r] |= ((u64)(u32)bin_) << (SHIFT); \
                G_l[r] = run_; cc_l[r] = run_ + c_; break; } \
            run_ += c_; } } \
} while (0)

// ---------- fused scores + EXACT top-64: histogram threshold + gather + sort ----------
__global__ __launch_bounds__(256) void score_topk_kernel(
    const char* __restrict__ q8, const char* __restrict__ kp8,
    const u32* __restrict__ scale_bits, const float* __restrict__ w,
    int* __restrict__ out) {
#pragma clang fp contract(off)
    __shared__ u32 qs_l[RPB][8];
    __shared__ float ts_l[RPB][HH];
    __shared__ float wt_l[HH];
    __shared__ u32 hist[RPB][HPAD];   // 17 KB
    __shared__ u64 cand[RPB][CAP];    // 16 KB
    __shared__ u32 cnt[RPB];
    __shared__ u64 T_l[RPB];
    __shared__ u32 G_l[RPB], cc_l[RPB];

    const int blk = blockIdx.x;
    const int row0 = blk * RPB;        // RPB rows, same batch (NQ % RPB == 0)
    const int b = row0 >> 12;
    const int t = threadIdx.x;
    const int lane = t & 63;
    const int wv = t >> 6;

    if (t < RPB) { cnt[t] = 0u; T_l[t] = 0ull; G_l[t] = 0u; cc_l[t] = NK; }
    if (t < RPB * 8) qs_l[t >> 3][t & 7] =
        ((const u32*)(q8 + (size_t)(row0 + (t >> 3)) * 32))[t & 7];
    if (t < RPB * HH) {
        int r = t >> 2, h = t & 3;
        float qsc = (__uint_as_float(scale_bits[b * 4 + h]) + 1e-6f) / 127.0f;
        float ksc = (__uint_as_float(scale_bits[8 + b * 4 + h]) + 1e-6f) / 127.0f;
        ts_l[r][h] = qsc * ksc;
        if (r == 0) wt_l[h] = w[h];
    }
    for (int i = t; i < RPB * HPAD; i += 256) (&hist[0][0])[i] = 0u;
    __syncthreads();

    const u32* kbase = (const u32*)(kp8 + (size_t)b * NK * 32);

    // Phase A: histogram key bits 63:54 (= score bits 31:22), all rows
    for (int i = 0; i < 32; ++i) {
        asm volatile("" ::: "memory");
        int n = t + i * 256;
        const u32* kr = kbase + (size_t)n * 8;
        uint4 c0 = *(const uint4*)(kr);
        uint4 c1 = *(const uint4*)(kr + 4);
#define DO_ROW(r) { u32 u; SCORE_U(r, u); u32 bin = u >> 22; \
        atomicAdd(&hist[r][bin + (bin >> 4)], 1u); }
        DO_ROW(0) DO_ROW(1) DO_ROW(2) DO_ROW(3)
#undef DO_ROW
    }
    __syncthreads();
    SELECT_PASS(wv, 54, 1024);

    // rare refinement: continue down the 64-bit key in 10-bit chunks
    const int shifts[6] = {44, 34, 24, 14, 4, 0};
    for (int p = 0; p < 6; ++p) {
        __syncthreads();
        bool need = (cc_l[0] > CAP) || (cc_l[1] > CAP) || (cc_l[2] > CAP) || (cc_l[3] > CAP);
        if (!need) break;
        const int shift = shifts[p];
        const int width = (shift == 0) ? 4 : 10;
        const u32 binmask = (1u << width) - 1u;
        const u64 himask = ~0ull << (shift + width);
        for (int i = t; i < RPB * HPAD; i += 256) (&hist[0][0])[i] = 0u;
        __syncthreads();
        for (int i = 0; i < 32; ++i) {
            asm volatile("" ::: "memory");
            int n = t + i * 256;
            const u32* kr = kbase + (size_t)n * 8;
            uint4 c0 = *(const uint4*)(kr);
            uint4 c1 = *(const uint4*)(kr + 4);
            u32 lo = 0xFFFFFFFFu - (u32)n;
#define DO_ROW(r) if (cc_l[r] > CAP) { u32 u; SCORE_U(r, u); \
            u64 kk = ((u64)u << 32) | (u64)lo; \
            if (((kk ^ T_l[r]) & himask) == 0ull) { \
                u32 bin = (u32)(kk >> shift) & binmask; \
                atomicAdd(&hist[r][bin + (bin >> 4)], 1u); } }
            DO_ROW(0) DO_ROW(1) DO_ROW(2) DO_ROW(3)
#undef DO_ROW
        }
        __syncthreads();
        if (cc_l[wv] > CAP) {
            if (width == 10) SELECT_PASS(wv, shift, 1024);
            else             SELECT_PASS(wv, shift, 16);
        }
    }
    __syncthreads();

    // Gather: all keys >= T (count == cc <= CAP per row)
    for (int i = 0; i < 32; ++i) {
        asm volatile("" ::: "memory");
        int n = t + i * 256;
        const u32* kr = kbase + (size_t)n * 8;
        uint4 c0 = *(const uint4*)(kr);
        uint4 c1 = *(const uint4*)(kr + 4);
        u32 lo = 0xFFFFFFFFu - (u32)n;
#define DO_ROW(r) { u32 u; SCORE_U(r, u); \
        u64 kk = ((u64)u << 32) | (u64)lo; \
        if (kk >= T_l[r]) { u32 pos = atomicAdd(&cnt[r], 1u); \
            if (pos < CAP) cand[r][pos] = kk; } }
        DO_ROW(0) DO_ROW(1) DO_ROW(2) DO_ROW(3)
#undef DO_ROW
    }
    __syncthreads();
    for (int i = t; i < RPB * CAP; i += 256) {
        int r = i >> 9, j = i & (CAP - 1);
        if ((u32)j >= cnt[r]) cand[r][j] = 0ull;
    }

    // bitonic sort (desc) of all RPB cand arrays simultaneously
    for (u32 k2 = 2; k2 <= CAP; k2 <<= 1) {
        for (u32 jj = k2 >> 1; jj > 0; jj >>= 1) {
            __syncthreads();
            for (int c = t; c < RPB * CAP; c += 256) {
                int r = c >> 9;
                u32 idx = (u32)(c & (CAP - 1));
                u32 partner = idx ^ jj;
                if (partner > idx) {
                    u64 a = cand[r][idx], d = cand[r][partner];
                    bool descBlock = ((idx & k2) == 0);
                    if (descBlock ? (a < d) : (a > d)) { cand[r][idx] = d; cand[r][partner] = a; }
                }
            }
        }
    }
    __syncthreads();

    if (t < RPB * TOPK) {
        int r = t >> 6, j = t & 63;
        out[(size_t)(row0 + r) * TOPK + j] = (int)(0xFFFFFFFFu - (u32)cand[r][j]);
    }
}

extern "C" void kernel_launch(void* const* d_in, const int* in_sizes, int n_in,
                              void* d_out, int out_size, void* d_ws, size_t ws_size,
                              hipStream_t stream) {
    const float* query = (const float*)d_in[0];
    const float* key = (const float*)d_in[1];
    const float* Wq = (const float*)d_in[2];
    const float* Wk = (const float*)d_in[3];
    const float* ow = (const float*)d_in[4];

    char* ws = (char*)d_ws;
    u32* scale_bits = (u32*)ws;
    char* q8 = ws + 1024;
    char* kp8 = q8 + BB * NQ * 32;
    int* out = (int*)d_out;

    (void)hipMemsetAsync(scale_bits, 0, 64, stream);

    const int nblocks = (BB * (NQ + NK)) / 16 * 2;  // 3072
    proj_absmax_kernel<<<nblocks, 256, 0, stream>>>(query, key, Wq, Wk, scale_bits);
    proj_quant_kernel<<<nblocks, 256, 0, stream>>>(query, key, Wq, Wk, scale_bits, q8, kp8);
    score_topk_kernel<<<(BB * NQ) / RPB, 256, 0, stream>>>(q8, kp8, scale_bits, ow, out);
}

// Round 21
// 372.014 us; speedup vs baseline: 1.9158x; 1.0328x over previous
//
#include <hip/hip_runtime.h>
#include <stdint.h>

#define BB 2
#define NQ 4096
#define NK 8192
#define DD 512
#define HH 4
#define TOPK 64
#define CAP 512
#define RPB 4        // rows per score block
#define HPAD 1088    // 1024 bins + bin>>4 padding

typedef unsigned int u32;
typedef unsigned long long u64;

#if defined(__has_builtin)
#if __has_builtin(__builtin_amdgcn_sdot4)
#define HAVE_SDOT4 1
#endif
#endif

__device__ __forceinline__ int dot4i8(u32 a, u32 b, int acc) {
#ifdef HAVE_SDOT4
    return __builtin_amdgcn_sdot4((int)a, (int)b, acc, false);
#else
    acc += (int)(signed char)(a & 0xFF) * (int)(signed char)(b & 0xFF);
    acc += (int)(signed char)((a >> 8) & 0xFF) * (int)(signed char)((b >> 8) & 0xFF);
    acc += (int)(signed char)((a >> 16) & 0xFF) * (int)(signed char)((b >> 16) & 0xFF);
    acc += (int)(signed char)((a >> 24) & 0xFF) * (int)(signed char)((b >> 24) & 0xFF);
    return acc;
#endif
}

// ---- GOLDEN accumulation order (verified bit-exact, round 13): 2-accumulator
// interleaved FMA chains (even/odd within each float4), one combining add.

#define PROJ_BODY(EMIT)                                                          \
    __shared__ float4 xs[16][128];                                               \
    __shared__ float4 wl[128][16];                                               \
    const int nqrows = BB * NQ;                                                  \
    int blk = blockIdx.x;                                                        \
    int half = blk & 1;                                                          \
    int row0 = (blk >> 1) << 4;                                                  \
    int type = (row0 >= nqrows);                                                 \
    int trow0 = type ? row0 - nqrows : row0;                                     \
    int b = type ? (trow0 >> 13) : (trow0 >> 12);                                \
    const float* X = type ? key : query;                                         \
    const float* W = type ? Wk : Wq;                                             \
    const int t = threadIdx.x;                                                   \
    {                                                                            \
        const float4* xg = (const float4*)(X + (size_t)trow0 * DD);              \
        float4* xsf = &xs[0][0];                                                 \
        for (int i = t; i < 2048; i += 256) xsf[i] = xg[i];                      \
        const float4* wg = (const float4*)W;                                     \
        for (int i = t; i < 2048; i += 256) {                                    \
            int oo = i & 15, jj = i >> 4;                                        \
            wl[jj][oo] = wg[(size_t)(half * 16 + oo) * 128 + jj];                \
        }                                                                        \
    }                                                                            \
    __syncthreads();                                                             \
    int o16 = t & 15, lr = t >> 4;                                               \
    int o = half * 16 + o16;                                                     \
    int h = o >> 3;                                                              \
    int trow = trow0 + lr;                                                       \
    float acc0 = 0.f, acc1 = 0.f;                                                \
    _Pragma("unroll 8")                                                          \
    for (int j = 0; j < 128; ++j) {                                              \
        float4 a = xs[lr][j];                                                    \
        float4 bb = wl[j][o16];                                                  \
        acc0 = fmaf(a.x, bb.x, acc0);                                            \
        acc1 = fmaf(a.y, bb.y, acc1);                                            \
        acc0 = fmaf(a.z, bb.z, acc0);                                            \
        acc1 = fmaf(a.w, bb.w, acc1);                                            \
    }                                                                            \
    float v = acc0 + acc1;                                                       \
    EMIT

__global__ __launch_bounds__(256, 2) void proj_absmax_kernel(
        const float* __restrict__ query, const float* __restrict__ key,
        const float* __restrict__ Wq, const float* __restrict__ Wk,
        u32* __restrict__ scale_bits) {
#pragma clang fp contract(off)
    __shared__ u32 lmax[4];
    if (threadIdx.x < 4) lmax[threadIdx.x] = 0u;
    PROJ_BODY(
        u32 bits = __float_as_uint(fabsf(v));
        __syncthreads();
        atomicMax(&lmax[h], bits);
        __syncthreads();
        if (threadIdx.x < 4 && lmax[threadIdx.x])
            atomicMax(&scale_bits[type * 8 + b * 4 + threadIdx.x], lmax[threadIdx.x]);
    )
}

__global__ __launch_bounds__(256, 2) void proj_quant_kernel(
        const float* __restrict__ query, const float* __restrict__ key,
        const float* __restrict__ Wq, const float* __restrict__ Wk,
        const u32* __restrict__ scale_bits,
        char* __restrict__ q8, char* __restrict__ kp8) {
#pragma clang fp contract(off)
    PROJ_BODY(
        float mx = __uint_as_float(scale_bits[type * 8 + b * 4 + h]);
        float scale = (mx + 1e-6f) / 127.0f;
        float r = rintf(v / scale);
        r = fminf(fmaxf(r, -127.f), 127.f);
        (type ? kp8 : q8)[(size_t)trow * 32 + o] = (char)(int)r;
    )
}

// mapped monotone score bits for row r from chunk regs c0,c1 (exact epilogue).
// q/ts/wt live in per-thread REGISTERS (qa[r][..], tsr[r][..], wtr[..]).
#define SCORE_U(r, udst) { \
    float acc = 0.f; \
    { int s = dot4i8(qa[r][0], c0.x, 0); s = dot4i8(qa[r][1], c0.y, s); \
      float sf = (float)s * tsr[r][0]; sf = fmaxf(sf, 0.f); \
      float pr = sf * wtr[0]; acc = acc + pr; } \
    { int s = dot4i8(qa[r][2], c0.z, 0); s = dot4i8(qa[r][3], c0.w, s); \
      float sf = (float)s * tsr[r][1]; sf = fmaxf(sf, 0.f); \
      float pr = sf * wtr[1]; acc = acc + pr; } \
    { int s = dot4i8(qa[r][4], c1.x, 0); s = dot4i8(qa[r][5], c1.y, s); \
      float sf = (float)s * tsr[r][2]; sf = fmaxf(sf, 0.f); \
      float pr = sf * wtr[2]; acc = acc + pr; } \
    { int s = dot4i8(qa[r][6], c1.z, 0); s = dot4i8(qa[r][7], c1.w, s); \
      float sf = (float)s * tsr[r][3]; sf = fmaxf(sf, 0.f); \
      float pr = sf * wtr[3]; acc = acc + pr; } \
    acc = acc + 0.0f; \
    u32 uu = __float_as_uint(acc); \
    udst = (uu & 0x80000000u) ? ~uu : (uu | 0x80000000u); }

// wave-local threshold selection over a filled histogram (run by wave wv==r)
#define SELECT_PASS(r, SHIFT, BINSN) do { \
    const int bpl_ = ((BINSN) >= 64) ? ((BINSN) / 64) : 1; \
    const int nact_ = ((BINSN) >= 64) ? 64 : (BINSN); \
    u32 P_ = 0u; \
    if (lane < nact_) { \
        for (int j_ = 0; j_ < bpl_; ++j_) { int bin_ = lane * bpl_ + j_; P_ += hist[r][bin_ + (bin_ >> 4)]; } } \
    u32 sI_ = P_; \
    for (int s_ = 1; s_ < 64; s_ <<= 1) { u32 o_ = __shfl_down(sI_, s_, 64); if (lane + s_ < 64) sI_ += o_; } \
    u32 sE_ = sI_ - P_; \
    u32 Gp_ = G_l[r]; \
    if (Gp_ + sE_ < TOPK && Gp_ + sI_ >= TOPK) { \
        u32 run_ = Gp_ + sE_; \
        for (int j_ = bpl_ - 1; j_ >= 0; --j_) { \
            int bin_ = lane * bpl_ + j_; u32 c_ = hist[r][bin_ + (bin_ >> 4)]; \
            if (run_ + c_ >= TOPK) { \
                T_l[r] |= ((u64)(u32)bin_) << (SHIFT); \
                G_l[r] = run_; cc_l[r] = run_ + c_; break; } \
            run_ += c_; } } \
} while (0)

// ---------- fused scores + EXACT top-64: histogram threshold + gather + sort ----------
__global__ __launch_bounds__(256) void score_topk_kernel(
    const char* __restrict__ q8, const char* __restrict__ kp8,
    const u32* __restrict__ scale_bits, const float* __restrict__ w,
    int* __restrict__ out) {
#pragma clang fp contract(off)
    __shared__ u32 hist[RPB][HPAD];   // 17 KB
    __shared__ u64 cand[RPB][CAP];    // 16 KB
    __shared__ u32 cnt[RPB];
    __shared__ u64 T_l[RPB];
    __shared__ u32 G_l[RPB], cc_l[RPB];

    const int blk = blockIdx.x;
    const int row0 = blk * RPB;        // RPB rows, same batch (NQ % RPB == 0)
    const int b = row0 >> 12;
    const int t = threadIdx.x;
    const int lane = t & 63;
    const int wv = t >> 6;

    if (t < RPB) { cnt[t] = 0u; T_l[t] = 0ull; G_l[t] = 0u; cc_l[t] = NK; }
    for (int i = t; i < RPB * HPAD; i += 256) (&hist[0][0])[i] = 0u;

    // q / total_scale / weights in registers
    u32 qa[RPB][8];
    float tsr[RPB][HH], wtr[HH];
#pragma unroll
    for (int r = 0; r < RPB; ++r) {
        const u32* qr = (const u32*)(q8 + (size_t)(row0 + r) * 32);
#pragma unroll
        for (int j = 0; j < 8; ++j) qa[r][j] = qr[j];
    }
#pragma unroll
    for (int h = 0; h < HH; ++h) {
        float qsc = (__uint_as_float(scale_bits[b * 4 + h]) + 1e-6f) / 127.0f;
        float ksc = (__uint_as_float(scale_bits[8 + b * 4 + h]) + 1e-6f) / 127.0f;
        float tsv = qsc * ksc;
#pragma unroll
        for (int r = 0; r < RPB; ++r) tsr[r][h] = tsv;
        wtr[h] = w[h];
    }
    __syncthreads();

    const u32* kbase = (const u32*)(kp8 + (size_t)b * NK * 32);

    // Phase A: histogram key bits 63:54 (= score bits 31:22), all rows
    for (int i = 0; i < 32; ++i) {
        int n = t + i * 256;
        const u32* kr = kbase + (size_t)n * 8;
        uint4 c0 = *(const uint4*)(kr);
        uint4 c1 = *(const uint4*)(kr + 4);
#define DO_ROW(r) { u32 u; SCORE_U(r, u); u32 bin = u >> 22; \
        atomicAdd(&hist[r][bin + (bin >> 4)], 1u); }
        DO_ROW(0) DO_ROW(1) DO_ROW(2) DO_ROW(3)
#undef DO_ROW
    }
    __syncthreads();
    SELECT_PASS(wv, 54, 1024);

    // rare refinement: continue down the 64-bit key in 10-bit chunks
    const int shifts[6] = {44, 34, 24, 14, 4, 0};
    for (int p = 0; p < 6; ++p) {
        __syncthreads();
        bool need = (cc_l[0] > CAP) || (cc_l[1] > CAP) || (cc_l[2] > CAP) || (cc_l[3] > CAP);
        if (!need) break;
        const int shift = shifts[p];
        const int width = (shift == 0) ? 4 : 10;
        const u32 binmask = (1u << width) - 1u;
        const u64 himask = ~0ull << (shift + width);
        for (int i = t; i < RPB * HPAD; i += 256) (&hist[0][0])[i] = 0u;
        __syncthreads();
        for (int i = 0; i < 32; ++i) {
            int n = t + i * 256;
            const u32* kr = kbase + (size_t)n * 8;
            uint4 c0 = *(const uint4*)(kr);
            uint4 c1 = *(const uint4*)(kr + 4);
            u32 lo = 0xFFFFFFFFu - (u32)n;
#define DO_ROW(r) if (cc_l[r] > CAP) { u32 u; SCORE_U(r, u); \
            u64 kk = ((u64)u << 32) | (u64)lo; \
            if (((kk ^ T_l[r]) & himask) == 0ull) { \
                u32 bin = (u32)(kk >> shift) & binmask; \
                atomicAdd(&hist[r][bin + (bin >> 4)], 1u); } }
            DO_ROW(0) DO_ROW(1) DO_ROW(2) DO_ROW(3)
#undef DO_ROW
        }
        __syncthreads();
        if (cc_l[wv] > CAP) {
            if (width == 10) SELECT_PASS(wv, shift, 1024);
            else             SELECT_PASS(wv, shift, 16);
        }
    }
    __syncthreads();

    // Gather: all keys >= T (count == cc <= CAP per row)
    for (int i = 0; i < 32; ++i) {
        int n = t + i * 256;
        const u32* kr = kbase + (size_t)n * 8;
        uint4 c0 = *(const uint4*)(kr);
        uint4 c1 = *(const uint4*)(kr + 4);
        u32 lo = 0xFFFFFFFFu - (u32)n;
#define DO_ROW(r) { u32 u; SCORE_U(r, u); \
        u64 kk = ((u64)u << 32) | (u64)lo; \
        if (kk >= T_l[r]) { u32 pos = atomicAdd(&cnt[r], 1u); \
            if (pos < CAP) cand[r][pos] = kk; } }
        DO_ROW(0) DO_ROW(1) DO_ROW(2) DO_ROW(3)
#undef DO_ROW
    }
    __syncthreads();
    for (int i = t; i < RPB * CAP; i += 256) {
        int r = i >> 9, j = i & (CAP - 1);
        if ((u32)j >= cnt[r]) cand[r][j] = 0ull;
    }

    // bitonic sort (desc) of all RPB cand arrays simultaneously
    for (u32 k2 = 2; k2 <= CAP; k2 <<= 1) {
        for (u32 jj = k2 >> 1; jj > 0; jj >>= 1) {
            __syncthreads();
            for (int c = t; c < RPB * CAP; c += 256) {
                int r = c >> 9;
                u32 idx = (u32)(c & (CAP - 1));
                u32 partner = idx ^ jj;
                if (partner > idx) {
                    u64 a = cand[r][idx], d = cand[r][partner];
                    bool descBlock = ((idx & k2) == 0);
                    if (descBlock ? (a < d) : (a > d)) { cand[r][idx] = d; cand[r][partner] = a; }
                }
            }
        }
    }
    __syncthreads();

    if (t < RPB * TOPK) {
        int r = t >> 6, j = t & 63;
        out[(size_t)(row0 + r) * TOPK + j] = (int)(0xFFFFFFFFu - (u32)cand[r][j]);
    }
}

extern "C" void kernel_launch(void* const* d_in, const int* in_sizes, int n_in,
                              void* d_out, int out_size, void* d_ws, size_t ws_size,
                              hipStream_t stream) {
    const float* query = (const float*)d_in[0];
    const float* key = (const float*)d_in[1];
    const float* Wq = (const float*)d_in[2];
    const float* Wk = (const float*)d_in[3];
    const float* ow = (const float*)d_in[4];

    char* ws = (char*)d_ws;
    u32* scale_bits = (u32*)ws;
    char* q8 = ws + 1024;
    char* kp8 = q8 + BB * NQ * 32;
    int* out = (int*)d_out;

    (void)hipMemsetAsync(scale_bits, 0, 64, stream);

    const int nblocks = (BB * (NQ + NK)) / 16 * 2;  // 3072
    proj_absmax_kernel<<<nblocks, 256, 0, stream>>>(query, key, Wq, Wk, scale_bits);
    proj_quant_kernel<<<nblocks, 256, 0, stream>>>(query, key, Wq, Wk, scale_bits, q8, kp8);
    score_topk_kernel<<<(BB * NQ) / RPB, 256, 0, stream>>>(q8, kp8, scale_bits, ow, out);
}

// Round 22
// 330.486 us; speedup vs baseline: 2.1565x; 1.1257x over previous
//
#include <hip/hip_runtime.h>
#include <stdint.h>

#define BB 2
#define NQ 4096
#define NK 8192
#define DD 512
#define HH 4
#define TOPK 64
#define CAP 256
#define RPB 2        // rows per score block
#define HPAD 1088    // 1024 bins + bin>>4 padding

typedef unsigned int u32;
typedef unsigned long long u64;

#if defined(__has_builtin)
#if __has_builtin(__builtin_amdgcn_sdot4)
#define HAVE_SDOT4 1
#endif
#endif

__device__ __forceinline__ int dot4i8(u32 a, u32 b, int acc) {
#ifdef HAVE_SDOT4
    return __builtin_amdgcn_sdot4((int)a, (int)b, acc, false);
#else
    acc += (int)(signed char)(a & 0xFF) * (int)(signed char)(b & 0xFF);
    acc += (int)(signed char)((a >> 8) & 0xFF) * (int)(signed char)((b >> 8) & 0xFF);
    acc += (int)(signed char)((a >> 16) & 0xFF) * (int)(signed char)((b >> 16) & 0xFF);
    acc += (int)(signed char)((a >> 24) & 0xFF) * (int)(signed char)((b >> 24) & 0xFF);
    return acc;
#endif
}

// ---- GOLDEN accumulation order (verified bit-exact, round 13): 2-accumulator
// interleaved FMA chains (even/odd within each float4), one combining add.

#define PROJ_BODY(EMIT)                                                          \
    __shared__ float4 xs[16][128];                                               \
    __shared__ float4 wl[128][16];                                               \
    const int nqrows = BB * NQ;                                                  \
    int blk = blockIdx.x;                                                        \
    int half = blk & 1;                                                          \
    int row0 = (blk >> 1) << 4;                                                  \
    int type = (row0 >= nqrows);                                                 \
    int trow0 = type ? row0 - nqrows : row0;                                     \
    int b = type ? (trow0 >> 13) : (trow0 >> 12);                                \
    const float* X = type ? key : query;                                         \
    const float* W = type ? Wk : Wq;                                             \
    const int t = threadIdx.x;                                                   \
    {                                                                            \
        const float4* xg = (const float4*)(X + (size_t)trow0 * DD);              \
        float4* xsf = &xs[0][0];                                                 \
        for (int i = t; i < 2048; i += 256) xsf[i] = xg[i];                      \
        const float4* wg = (const float4*)W;                                     \
        for (int i = t; i < 2048; i += 256) {                                    \
            int oo = i & 15, jj = i >> 4;                                        \
            wl[jj][oo] = wg[(size_t)(half * 16 + oo) * 128 + jj];                \
        }                                                                        \
    }                                                                            \
    __syncthreads();                                                             \
    int o16 = t & 15, lr = t >> 4;                                               \
    int o = half * 16 + o16;                                                     \
    int h = o >> 3;                                                              \
    int trow = trow0 + lr;                                                       \
    float acc0 = 0.f, acc1 = 0.f;                                                \
    _Pragma("unroll 8")                                                          \
    for (int j = 0; j < 128; ++j) {                                              \
        float4 a = xs[lr][j];                                                    \
        float4 bb = wl[j][o16];                                                  \
        acc0 = fmaf(a.x, bb.x, acc0);                                            \
        acc1 = fmaf(a.y, bb.y, acc1);                                            \
        acc0 = fmaf(a.z, bb.z, acc0);                                            \
        acc1 = fmaf(a.w, bb.w, acc1);                                            \
    }                                                                            \
    float v = acc0 + acc1;                                                       \
    EMIT

// Pass 1 (cached): projection + absmax + store f32 projection to ws
__global__ __launch_bounds__(256, 2) void proj_absmax_cached_kernel(
        const float* __restrict__ query, const float* __restrict__ key,
        const float* __restrict__ Wq, const float* __restrict__ Wk,
        u32* __restrict__ scale_bits,
        float* __restrict__ qf, float* __restrict__ kf) {
#pragma clang fp contract(off)
    __shared__ u32 lmax[4];
    if (threadIdx.x < 4) lmax[threadIdx.x] = 0u;
    PROJ_BODY(
        (type ? kf : qf)[(size_t)trow * 32 + o] = v;
        u32 bits = __float_as_uint(fabsf(v));
        __syncthreads();
        atomicMax(&lmax[h], bits);
        __syncthreads();
        if (threadIdx.x < 4 && lmax[threadIdx.x])
            atomicMax(&scale_bits[type * 8 + b * 4 + threadIdx.x], lmax[threadIdx.x]);
    )
}

// Pass 1 (fallback): projection + absmax only
__global__ __launch_bounds__(256, 2) void proj_absmax_kernel(
        const float* __restrict__ query, const float* __restrict__ key,
        const float* __restrict__ Wq, const float* __restrict__ Wk,
        u32* __restrict__ scale_bits) {
#pragma clang fp contract(off)
    __shared__ u32 lmax[4];
    if (threadIdx.x < 4) lmax[threadIdx.x] = 0u;
    PROJ_BODY(
        u32 bits = __float_as_uint(fabsf(v));
        __syncthreads();
        atomicMax(&lmax[h], bits);
        __syncthreads();
        if (threadIdx.x < 4 && lmax[threadIdx.x])
            atomicMax(&scale_bits[type * 8 + b * 4 + threadIdx.x], lmax[threadIdx.x]);
    )
}

// Pass 2 (cached): read stored f32 projection, quantize (elementwise)
__global__ __launch_bounds__(256) void quant_cached_kernel(
        const float* __restrict__ qf, const float* __restrict__ kf,
        const u32* __restrict__ scale_bits,
        char* __restrict__ q8, char* __restrict__ kp8) {
#pragma clang fp contract(off)
    const int nq = BB * NQ * 32;
    int gid = blockIdx.x * 256 + threadIdx.x;
    int type = (gid >= nq);
    int idx = type ? gid - nq : gid;
    int h = (idx >> 3) & 3;
    int b = type ? (idx >> 18) : (idx >> 17);
    float v = (type ? kf : qf)[idx];
    float mx = __uint_as_float(scale_bits[type * 8 + b * 4 + h]);
    float scale = (mx + 1e-6f) / 127.0f;
    float r = rintf(v / scale);
    r = fminf(fmaxf(r, -127.f), 127.f);
    (type ? kp8 : q8)[idx] = (char)(int)r;
}

// Pass 2 (fallback): recompute projection, quantize
__global__ __launch_bounds__(256, 2) void proj_quant_kernel(
        const float* __restrict__ query, const float* __restrict__ key,
        const float* __restrict__ Wq, const float* __restrict__ Wk,
        const u32* __restrict__ scale_bits,
        char* __restrict__ q8, char* __restrict__ kp8) {
#pragma clang fp contract(off)
    PROJ_BODY(
        float mx = __uint_as_float(scale_bits[type * 8 + b * 4 + h]);
        float scale = (mx + 1e-6f) / 127.0f;
        float r = rintf(v / scale);
        r = fminf(fmaxf(r, -127.f), 127.f);
        (type ? kp8 : q8)[(size_t)trow * 32 + o] = (char)(int)r;
    )
}

// mapped monotone score bits for row r from chunk regs c0,c1 (exact epilogue)
#define SCORE_U(r, udst) { \
    float acc = 0.f; \
    { int s = dot4i8(qa[r][0], c0.x, 0); s = dot4i8(qa[r][1], c0.y, s); \
      float sf = (float)s * tsr[r][0]; sf = fmaxf(sf, 0.f); \
      float pr = sf * wtr[0]; acc = acc + pr; } \
    { int s = dot4i8(qa[r][2], c0.z, 0); s = dot4i8(qa[r][3], c0.w, s); \
      float sf = (float)s * tsr[r][1]; sf = fmaxf(sf, 0.f); \
      float pr = sf * wtr[1]; acc = acc + pr; } \
    { int s = dot4i8(qa[r][4], c1.x, 0); s = dot4i8(qa[r][5], c1.y, s); \
      float sf = (float)s * tsr[r][2]; sf = fmaxf(sf, 0.f); \
      float pr = sf * wtr[2]; acc = acc + pr; } \
    { int s = dot4i8(qa[r][6], c1.z, 0); s = dot4i8(qa[r][7], c1.w, s); \
      float sf = (float)s * tsr[r][3]; sf = fmaxf(sf, 0.f); \
      float pr = sf * wtr[3]; acc = acc + pr; } \
    acc = acc + 0.0f; \
    u32 uu = __float_as_uint(acc); \
    udst = (uu & 0x80000000u) ? ~uu : (uu | 0x80000000u); }

// wave-local threshold selection over a filled histogram (run by wave wv==r)
#define SELECT_PASS(r, SHIFT, BINSN) do { \
    const int bpl_ = ((BINSN) >= 64) ? ((BINSN) / 64) : 1; \
    const int nact_ = ((BINSN) >= 64) ? 64 : (BINSN); \
    u32 P_ = 0u; \
    if (lane < nact_) { \
        for (int j_ = 0; j_ < bpl_; ++j_) { int bin_ = lane * bpl_ + j_; P_ += hist[r][bin_ + (bin_ >> 4)]; } } \
    u32 sI_ = P_; \
    for (int s_ = 1; s_ < 64; s_ <<= 1) { u32 o_ = __shfl_down(sI_, s_, 64); if (lane + s_ < 64) sI_ += o_; } \
    u32 sE_ = sI_ - P_; \
    u32 Gp_ = G_l[r]; \
    if (Gp_ + sE_ < TOPK && Gp_ + sI_ >= TOPK) { \
        u32 run_ = Gp_ + sE_; \
        for (int j_ = bpl_ - 1; j_ >= 0; --j_) { \
            int bin_ = lane * bpl_ + j_; u32 c_ = hist[r][bin_ + (bin_ >> 4)]; \
            if (run_ + c_ >= TOPK) { \
                T_l[r] |= ((u64)(u32)bin_) << (SHIFT); \
                G_l[r] = run_; cc_l[r] = run_ + c_; break; } \
            run_ += c_; } } \
} while (0)

// ---------- fused scores (computed ONCE, cached in LDS) + EXACT top-64 ----------
__global__ __launch_bounds__(256) void score_topk_kernel(
    const char* __restrict__ q8, const char* __restrict__ kp8,
    const u32* __restrict__ scale_bits, const float* __restrict__ w,
    int* __restrict__ out) {
#pragma clang fp contract(off)
    __shared__ u32 scores[RPB][NK];   // 64 KB: monotone-mapped score bits
    __shared__ u32 hist[RPB][HPAD];   // 8.7 KB
    __shared__ u64 cand[RPB][CAP];    // 4 KB
    __shared__ u32 cnt[RPB];
    __shared__ u64 T_l[RPB];
    __shared__ u32 G_l[RPB], cc_l[RPB];

    const int blk = blockIdx.x;
    const int row0 = blk * RPB;        // RPB rows, same batch
    const int b = row0 >> 12;
    const int t = threadIdx.x;
    const int lane = t & 63;
    const int wv = t >> 6;

    if (t < RPB) { cnt[t] = 0u; T_l[t] = 0ull; G_l[t] = 0u; cc_l[t] = NK; }
    for (int i = t; i < RPB * HPAD; i += 256) (&hist[0][0])[i] = 0u;

    // q / total_scale / weights in registers
    u32 qa[RPB][8];
    float tsr[RPB][HH], wtr[HH];
#pragma unroll
    for (int r = 0; r < RPB; ++r) {
        const u32* qr = (const u32*)(q8 + (size_t)(row0 + r) * 32);
#pragma unroll
        for (int j = 0; j < 8; ++j) qa[r][j] = qr[j];
    }
#pragma unroll
    for (int h = 0; h < HH; ++h) {
        float qsc = (__uint_as_float(scale_bits[b * 4 + h]) + 1e-6f) / 127.0f;
        float ksc = (__uint_as_float(scale_bits[8 + b * 4 + h]) + 1e-6f) / 127.0f;
        float tsv = qsc * ksc;
#pragma unroll
        for (int r = 0; r < RPB; ++r) tsr[r][h] = tsv;
        wtr[h] = w[h];
    }
    __syncthreads();

    const u32* kbase = (const u32*)(kp8 + (size_t)b * NK * 32);

    // Phase A: compute scores ONCE, store in LDS, histogram key bits 63:54
    for (int i = 0; i < 32; ++i) {
        int n = t + i * 256;
        const u32* kr = kbase + (size_t)n * 8;
        uint4 c0 = *(const uint4*)(kr);
        uint4 c1 = *(const uint4*)(kr + 4);
#define DO_ROW(r) { u32 u; SCORE_U(r, u); scores[r][n] = u; u32 bin = u >> 22; \
        atomicAdd(&hist[r][bin + (bin >> 4)], 1u); }
        DO_ROW(0) DO_ROW(1)
#undef DO_ROW
    }
    __syncthreads();
    if (wv < RPB) SELECT_PASS(wv, 54, 1024);

    // refinement down the 64-bit key in 10-bit chunks (reads cached scores)
    const int shifts[6] = {44, 34, 24, 14, 4, 0};
    for (int p = 0; p < 6; ++p) {
        __syncthreads();
        bool need = (cc_l[0] > CAP) || (cc_l[1] > CAP);
        if (!need) break;
        const int shift = shifts[p];
        const int width = (shift == 0) ? 4 : 10;
        const u32 binmask = (1u << width) - 1u;
        const u64 himask = ~0ull << (shift + width);
        for (int i = t; i < RPB * HPAD; i += 256) (&hist[0][0])[i] = 0u;
        __syncthreads();
        for (int i = 0; i < 32; ++i) {
            int n = t + i * 256;
            u32 lo = 0xFFFFFFFFu - (u32)n;
#define DO_ROW(r) if (cc_l[r] > CAP) { \
            u64 kk = ((u64)scores[r][n] << 32) | (u64)lo; \
            if (((kk ^ T_l[r]) & himask) == 0ull) { \
                u32 bin = (u32)(kk >> shift) & binmask; \
                atomicAdd(&hist[r][bin + (bin >> 4)], 1u); } }
            DO_ROW(0) DO_ROW(1)
#undef DO_ROW
        }
        __syncthreads();
        if (wv < RPB && cc_l[wv] > CAP) {
            if (width == 10) SELECT_PASS(wv, shift, 1024);
            else             SELECT_PASS(wv, shift, 16);
        }
    }
    __syncthreads();

    // Gather from cached scores: all keys >= T (count cc <= CAP per row)
    for (int i = 0; i < 32; ++i) {
        int n = t + i * 256;
        u32 lo = 0xFFFFFFFFu - (u32)n;
#define DO_ROW(r) { u64 kk = ((u64)scores[r][n] << 32) | (u64)lo; \
        if (kk >= T_l[r]) { u32 pos = atomicAdd(&cnt[r], 1u); \
            if (pos < CAP) cand[r][pos] = kk; } }
        DO_ROW(0) DO_ROW(1)
#undef DO_ROW
    }
    __syncthreads();
    for (int i = t; i < RPB * CAP; i += 256) {
        int r = i >> 8, j = i & (CAP - 1);
        if ((u32)j >= cnt[r]) cand[r][j] = 0ull;
    }

    // bitonic sort (desc) of all RPB cand arrays simultaneously
    for (u32 k2 = 2; k2 <= CAP; k2 <<= 1) {
        for (u32 jj = k2 >> 1; jj > 0; jj >>= 1) {
            __syncthreads();
            for (int c = t; c < RPB * CAP; c += 256) {
                int r = c >> 8;
                u32 idx = (u32)(c & (CAP - 1));
                u32 partner = idx ^ jj;
                if (partner > idx) {
                    u64 a = cand[r][idx], d = cand[r][partner];
                    bool descBlock = ((idx & k2) == 0);
                    if (descBlock ? (a < d) : (a > d)) { cand[r][idx] = d; cand[r][partner] = a; }
                }
            }
        }
    }
    __syncthreads();

    if (t < RPB * TOPK) {
        int r = t >> 6, j = t & 63;
        out[(size_t)(row0 + r) * TOPK + j] = (int)(0xFFFFFFFFu - (u32)cand[r][j]);
    }
}

extern "C" void kernel_launch(void* const* d_in, const int* in_sizes, int n_in,
                              void* d_out, int out_size, void* d_ws, size_t ws_size,
                              hipStream_t stream) {
    const float* query = (const float*)d_in[0];
    const float* key = (const float*)d_in[1];
    const float* Wq = (const float*)d_in[2];
    const float* Wk = (const float*)d_in[3];
    const float* ow = (const float*)d_in[4];

    char* ws = (char*)d_ws;
    u32* scale_bits = (u32*)ws;
    char* q8 = ws + 1024;
    char* kp8 = q8 + BB * NQ * 32;                 // 256 KB
    float* qf = (float*)(ws + 1024 + 768 * 1024);  // 1 MB
    float* kf = qf + BB * NQ * 32;                 // 2 MB
    int* out = (int*)d_out;

    (void)hipMemsetAsync(scale_bits, 0, 64, stream);

    const size_t need = 1024 + 768 * 1024 + 3 * 1024 * 1024;
    const int nblocks = (BB * (NQ + NK)) / 16 * 2;  // 3072
    const int total_elems = BB * (NQ + NK) * 32;    // 786432
    if (ws_size >= need) {
        proj_absmax_cached_kernel<<<nblocks, 256, 0, stream>>>(query, key, Wq, Wk,
                                                               scale_bits, qf, kf);
        quant_cached_kernel<<<total_elems / 256, 256, 0, stream>>>(qf, kf, scale_bits, q8, kp8);
    } else {
        proj_absmax_kernel<<<nblocks, 256, 0, stream>>>(query, key, Wq, Wk, scale_bits);
        proj_quant_kernel<<<nblocks, 256, 0, stream>>>(query, key, Wq, Wk, scale_bits, q8, kp8);
    }
    score_topk_kernel<<<(BB * NQ) / RPB, 256, 0, stream>>>(q8, kp8, scale_bits, ow, out);
}

// Round 23
// 222.796 us; speedup vs baseline: 3.1989x; 1.4834x over previous
//
#include <hip/hip_runtime.h>
#include <stdint.h>

#define BB 2
#define NQ 4096
#define NK 8192
#define DD 512
#define HH 4
#define TOPK 64
#define CAP 256
#define RPB 2        // rows per score block
#define BLK 512      // threads per score block
#define HPAD 1088    // 1024 bins + bin>>4 padding
#define SENT 0xFFFFFFFFu
#define ZBOUND 0x80000000FFFFFFFFull  // max key a nonpositive score can have

typedef unsigned int u32;
typedef unsigned long long u64;

#if defined(__has_builtin)
#if __has_builtin(__builtin_amdgcn_sdot4)
#define HAVE_SDOT4 1
#endif
#endif

__device__ __forceinline__ int dot4i8(u32 a, u32 b, int acc) {
#ifdef HAVE_SDOT4
    return __builtin_amdgcn_sdot4((int)a, (int)b, acc, false);
#else
    acc += (int)(signed char)(a & 0xFF) * (int)(signed char)(b & 0xFF);
    acc += (int)(signed char)((a >> 8) & 0xFF) * (int)(signed char)((b >> 8) & 0xFF);
    acc += (int)(signed char)((a >> 16) & 0xFF) * (int)(signed char)((b >> 16) & 0xFF);
    acc += (int)(signed char)((a >> 24) & 0xFF) * (int)(signed char)((b >> 24) & 0xFF);
    return acc;
#endif
}

// ---- GOLDEN accumulation order (verified bit-exact, round 13): 2-accumulator
// interleaved FMA chains (even/odd within each float4), one combining add.

#define PROJ_BODY(EMIT)                                                          \
    __shared__ float4 xs[16][128];                                               \
    __shared__ float4 wl[128][16];                                               \
    const int nqrows = BB * NQ;                                                  \
    int blk = blockIdx.x;                                                        \
    int half = blk & 1;                                                          \
    int row0 = (blk >> 1) << 4;                                                  \
    int type = (row0 >= nqrows);                                                 \
    int trow0 = type ? row0 - nqrows : row0;                                     \
    int b = type ? (trow0 >> 13) : (trow0 >> 12);                                \
    const float* X = type ? key : query;                                         \
    const float* W = type ? Wk : Wq;                                             \
    const int t = threadIdx.x;                                                   \
    {                                                                            \
        const float4* xg = (const float4*)(X + (size_t)trow0 * DD);              \
        float4* xsf = &xs[0][0];                                                 \
        for (int i = t; i < 2048; i += 256) xsf[i] = xg[i];                      \
        const float4* wg = (const float4*)W;                                     \
        for (int i = t; i < 2048; i += 256) {                                    \
            int oo = i & 15, jj = i >> 4;                                        \
            wl[jj][oo] = wg[(size_t)(half * 16 + oo) * 128 + jj];                \
        }                                                                        \
    }                                                                            \
    __syncthreads();                                                             \
    int o16 = t & 15, lr = t >> 4;                                               \
    int o = half * 16 + o16;                                                     \
    int h = o >> 3;                                                              \
    int trow = trow0 + lr;                                                       \
    float acc0 = 0.f, acc1 = 0.f;                                                \
    _Pragma("unroll 8")                                                          \
    for (int j = 0; j < 128; ++j) {                                              \
        float4 a = xs[lr][j];                                                    \
        float4 bb = wl[j][o16];                                                  \
        acc0 = fmaf(a.x, bb.x, acc0);                                            \
        acc1 = fmaf(a.y, bb.y, acc1);                                            \
        acc0 = fmaf(a.z, bb.z, acc0);                                            \
        acc1 = fmaf(a.w, bb.w, acc1);                                            \
    }                                                                            \
    float v = acc0 + acc1;                                                       \
    EMIT

__global__ __launch_bounds__(256, 2) void proj_absmax_cached_kernel(
        const float* __restrict__ query, const float* __restrict__ key,
        const float* __restrict__ Wq, const float* __restrict__ Wk,
        u32* __restrict__ scale_bits,
        float* __restrict__ qf, float* __restrict__ kf) {
#pragma clang fp contract(off)
    __shared__ u32 lmax[4];
    if (threadIdx.x < 4) lmax[threadIdx.x] = 0u;
    PROJ_BODY(
        (type ? kf : qf)[(size_t)trow * 32 + o] = v;
        u32 bits = __float_as_uint(fabsf(v));
        __syncthreads();
        atomicMax(&lmax[h], bits);
        __syncthreads();
        if (threadIdx.x < 4 && lmax[threadIdx.x])
            atomicMax(&scale_bits[type * 8 + b * 4 + threadIdx.x], lmax[threadIdx.x]);
    )
}

__global__ __launch_bounds__(256, 2) void proj_absmax_kernel(
        const float* __restrict__ query, const float* __restrict__ key,
        const float* __restrict__ Wq, const float* __restrict__ Wk,
        u32* __restrict__ scale_bits) {
#pragma clang fp contract(off)
    __shared__ u32 lmax[4];
    if (threadIdx.x < 4) lmax[threadIdx.x] = 0u;
    PROJ_BODY(
        u32 bits = __float_as_uint(fabsf(v));
        __syncthreads();
        atomicMax(&lmax[h], bits);
        __syncthreads();
        if (threadIdx.x < 4 && lmax[threadIdx.x])
            atomicMax(&scale_bits[type * 8 + b * 4 + threadIdx.x], lmax[threadIdx.x]);
    )
}

__global__ __launch_bounds__(256) void quant_cached_kernel(
        const float* __restrict__ qf, const float* __restrict__ kf,
        const u32* __restrict__ scale_bits,
        char* __restrict__ q8, char* __restrict__ kp8) {
#pragma clang fp contract(off)
    const int nq = BB * NQ * 32;
    int gid = blockIdx.x * 256 + threadIdx.x;
    int type = (gid >= nq);
    int idx = type ? gid - nq : gid;
    int h = (idx >> 3) & 3;
    int b = type ? (idx >> 18) : (idx >> 17);
    float v = (type ? kf : qf)[idx];
    float mx = __uint_as_float(scale_bits[type * 8 + b * 4 + h]);
    float scale = (mx + 1e-6f) / 127.0f;
    float r = rintf(v / scale);
    r = fminf(fmaxf(r, -127.f), 127.f);
    (type ? kp8 : q8)[idx] = (char)(int)r;
}

__global__ __launch_bounds__(256, 2) void proj_quant_kernel(
        const float* __restrict__ query, const float* __restrict__ key,
        const float* __restrict__ Wq, const float* __restrict__ Wk,
        const u32* __restrict__ scale_bits,
        char* __restrict__ q8, char* __restrict__ kp8) {
#pragma clang fp contract(off)
    PROJ_BODY(
        float mx = __uint_as_float(scale_bits[type * 8 + b * 4 + h]);
        float scale = (mx + 1e-6f) / 127.0f;
        float r = rintf(v / scale);
        r = fminf(fmaxf(r, -127.f), 127.f);
        (type ? kp8 : q8)[(size_t)trow * 32 + o] = (char)(int)r;
    )
}

// mapped monotone score bits for row r from chunk regs c0,c1 (exact epilogue)
#define SCORE_U(r, udst) { \
    float acc = 0.f; \
    { int s = dot4i8(qa[r][0], c0.x, 0); s = dot4i8(qa[r][1], c0.y, s); \
      float sf = (float)s * tsr[r][0]; sf = fmaxf(sf, 0.f); \
      float pr = sf * wtr[0]; acc = acc + pr; } \
    { int s = dot4i8(qa[r][2], c0.z, 0); s = dot4i8(qa[r][3], c0.w, s); \
      float sf = (float)s * tsr[r][1]; sf = fmaxf(sf, 0.f); \
      float pr = sf * wtr[1]; acc = acc + pr; } \
    { int s = dot4i8(qa[r][4], c1.x, 0); s = dot4i8(qa[r][5], c1.y, s); \
      float sf = (float)s * tsr[r][2]; sf = fmaxf(sf, 0.f); \
      float pr = sf * wtr[2]; acc = acc + pr; } \
    { int s = dot4i8(qa[r][6], c1.z, 0); s = dot4i8(qa[r][7], c1.w, s); \
      float sf = (float)s * tsr[r][3]; sf = fmaxf(sf, 0.f); \
      float pr = sf * wtr[3]; acc = acc + pr; } \
    acc = acc + 0.0f; \
    u32 uu = __float_as_uint(acc); \
    udst = (uu & 0x80000000u) ? ~uu : (uu | 0x80000000u); }

// wave-local threshold selection over a filled histogram (run by wave wv==r)
#define SELECT_PASS(r, SHIFT, BINSN) do { \
    const int bpl_ = ((BINSN) >= 64) ? ((BINSN) / 64) : 1; \
    const int nact_ = ((BINSN) >= 64) ? 64 : (BINSN); \
    u32 P_ = 0u; \
    if (lane < nact_) { \
        for (int j_ = 0; j_ < bpl_; ++j_) { int bin_ = lane * bpl_ + j_; P_ += hist[r][bin_ + (bin_ >> 4)]; } } \
    u32 sI_ = P_; \
    for (int s_ = 1; s_ < 64; s_ <<= 1) { u32 o_ = __shfl_down(sI_, s_, 64); if (lane + s_ < 64) sI_ += o_; } \
    u32 sE_ = sI_ - P_; \
    u32 Gp_ = G_l[r]; \
    if (Gp_ + sE_ < TOPK && Gp_ + sI_ >= TOPK) { \
        u32 run_ = Gp_ + sE_; \
        for (int j_ = bpl_ - 1; j_ >= 0; --j_) { \
            int bin_ = lane * bpl_ + j_; u32 c_ = hist[r][bin_ + (bin_ >> 4)]; \
            if (run_ + c_ >= TOPK) { \
                T_l[r] |= ((u64)(u32)bin_) << (SHIFT); \
                G_l[r] = run_; cc_l[r] = run_ + c_; break; } \
            run_ += c_; } } \
} while (0)

// ---------- fused scores (computed once, cached) + EXACT top-64 ----------
__global__ __launch_bounds__(BLK) void score_topk_kernel(
    const char* __restrict__ q8, const char* __restrict__ kp8,
    const u32* __restrict__ scale_bits, const float* __restrict__ w,
    int* __restrict__ out) {
#pragma clang fp contract(off)
    __shared__ u32 scores[RPB][NK];   // 64 KB
    __shared__ u32 hist[RPB][HPAD];   // 8.7 KB
    __shared__ u64 cand[RPB][CAP];    // 4 KB
    __shared__ u32 cnt[RPB];
    __shared__ u64 T_l[RPB];
    __shared__ u32 G_l[RPB], cc_l[RPB];

    const int blk = blockIdx.x;
    const int row0 = blk * RPB;
    const int b = row0 >> 12;
    const int t = threadIdx.x;
    const int lane = t & 63;
    const int wv = t >> 6;

    if (t < RPB) { cnt[t] = 0u; T_l[t] = 0ull; G_l[t] = 0u; cc_l[t] = SENT; }
    for (int i = t; i < RPB * HPAD; i += BLK) (&hist[0][0])[i] = 0u;

    u32 qa[RPB][8];
    float tsr[RPB][HH], wtr[HH];
#pragma unroll
    for (int r = 0; r < RPB; ++r) {
        const u32* qr = (const u32*)(q8 + (size_t)(row0 + r) * 32);
#pragma unroll
        for (int j = 0; j < 8; ++j) qa[r][j] = qr[j];
    }
#pragma unroll
    for (int h = 0; h < HH; ++h) {
        float qsc = (__uint_as_float(scale_bits[b * 4 + h]) + 1e-6f) / 127.0f;
        float ksc = (__uint_as_float(scale_bits[8 + b * 4 + h]) + 1e-6f) / 127.0f;
        float tsv = qsc * ksc;
#pragma unroll
        for (int r = 0; r < RPB; ++r) tsr[r][h] = tsv;
        wtr[h] = w[h];
    }
    __syncthreads();

    const u32* kbase = (const u32*)(kp8 + (size_t)b * NK * 32);

    // Phase A: compute scores ONCE, cache in LDS; histogram POSITIVE scores only
    for (int i = 0; i < NK / BLK; ++i) {
        int n = t + i * BLK;
        const u32* kr = kbase + (size_t)n * 8;
        uint4 c0 = *(const uint4*)(kr);
        uint4 c1 = *(const uint4*)(kr + 4);
#define DO_ROW(r) { u32 u; SCORE_U(r, u); scores[r][n] = u; \
        if (u > 0x80000000u) { u32 bin = u >> 22; \
            atomicAdd(&hist[r][bin + (bin >> 4)], 1u); } }
        DO_ROW(0) DO_ROW(1)
#undef DO_ROW
    }
    __syncthreads();
    if (wv < RPB) SELECT_PASS(wv, 54, 1024);
    __syncthreads();

    // Exactness fallback (never taken on real data): select failed (<64
    // positives) or threshold touches the zero boundary (zeros would leak
    // past gather). Redo with a FULL histogram.
    {
        bool f0 = (cc_l[0] == SENT) || (T_l[0] <= ZBOUND);
        bool f1 = (cc_l[1] == SENT) || (T_l[1] <= ZBOUND);
        if (f0 || f1) {
            if (t == 0) {
                if (f0) { T_l[0] = 0ull; G_l[0] = 0u; cc_l[0] = SENT; }
                if (f1) { T_l[1] = 0ull; G_l[1] = 0u; cc_l[1] = SENT; }
            }
            for (int i = t; i < RPB * HPAD; i += BLK) (&hist[0][0])[i] = 0u;
            __syncthreads();
            for (int i = 0; i < NK / BLK; ++i) {
                int n = t + i * BLK;
                if (f0) { u32 u = scores[0][n]; u32 bin = u >> 22;
                          atomicAdd(&hist[0][bin + (bin >> 4)], 1u); }
                if (f1) { u32 u = scores[1][n]; u32 bin = u >> 22;
                          atomicAdd(&hist[1][bin + (bin >> 4)], 1u); }
            }
            __syncthreads();
            if (wv == 0 && f0) SELECT_PASS(0, 54, 1024);
            if (wv == 1 && f1) SELECT_PASS(1, 54, 1024);
            __syncthreads();
        }
    }

    // refinement down the 64-bit key in 10-bit chunks (reads cached scores)
    const int shifts[6] = {44, 34, 24, 14, 4, 0};
    for (int p = 0; p < 6; ++p) {
        __syncthreads();
        if (!((cc_l[0] > CAP) || (cc_l[1] > CAP))) break;
        const int shift = shifts[p];
        const int width = (shift == 0) ? 4 : 10;
        const u32 binmask = (1u << width) - 1u;
        const u64 himask = ~0ull << (shift + width);
        for (int i = t; i < RPB * HPAD; i += BLK) (&hist[0][0])[i] = 0u;
        __syncthreads();
        for (int i = 0; i < NK / BLK; ++i) {
            int n = t + i * BLK;
            u32 lo = 0xFFFFFFFFu - (u32)n;
#define DO_ROW(r) if (cc_l[r] > CAP) { \
            u64 kk = ((u64)scores[r][n] << 32) | (u64)lo; \
            if (((kk ^ T_l[r]) & himask) == 0ull) { \
                u32 bin = (u32)(kk >> shift) & binmask; \
                atomicAdd(&hist[r][bin + (bin >> 4)], 1u); } }
            DO_ROW(0) DO_ROW(1)
#undef DO_ROW
        }
        __syncthreads();
        if (wv < RPB && cc_l[wv] > CAP) {
            if (width == 10) SELECT_PASS(wv, shift, 1024);
            else             SELECT_PASS(wv, shift, 16);
        }
    }
    __syncthreads();

    // Gather from cached scores: all keys >= T (count cc <= CAP per row)
    for (int i = 0; i < NK / BLK; ++i) {
        int n = t + i * BLK;
        u32 lo = 0xFFFFFFFFu - (u32)n;
#define DO_ROW(r) { u64 kk = ((u64)scores[r][n] << 32) | (u64)lo; \
        if (kk >= T_l[r]) { u32 pos = atomicAdd(&cnt[r], 1u); \
            if (pos < CAP) cand[r][pos] = kk; } }
        DO_ROW(0) DO_ROW(1)
#undef DO_ROW
    }
    __syncthreads();
    for (int i = t; i < RPB * CAP; i += BLK) {
        int r = i >> 8, j = i & (CAP - 1);
        if ((u32)j >= cnt[r]) cand[r][j] = 0ull;
    }

    // bitonic sort (desc), both rows simultaneously: 1 element per thread
    for (u32 k2 = 2; k2 <= CAP; k2 <<= 1) {
        for (u32 jj = k2 >> 1; jj > 0; jj >>= 1) {
            __syncthreads();
            {
                int c = t;
                int r = c >> 8;
                u32 idx = (u32)(c & (CAP - 1));
                u32 partner = idx ^ jj;
                if (partner > idx) {
                    u64 a = cand[r][idx], d = cand[r][partner];
                    bool descBlock = ((idx & k2) == 0);
                    if (descBlock ? (a < d) : (a > d)) { cand[r][idx] = d; cand[r][partner] = a; }
                }
            }
        }
    }
    __syncthreads();

    if (t < RPB * TOPK) {
        int r = t >> 6, j = t & 63;
        out[(size_t)(row0 + r) * TOPK + j] = (int)(0xFFFFFFFFu - (u32)cand[r][j]);
    }
}

extern "C" void kernel_launch(void* const* d_in, const int* in_sizes, int n_in,
                              void* d_out, int out_size, void* d_ws, size_t ws_size,
                              hipStream_t stream) {
    const float* query = (const float*)d_in[0];
    const float* key = (const float*)d_in[1];
    const float* Wq = (const float*)d_in[2];
    const float* Wk = (const float*)d_in[3];
    const float* ow = (const float*)d_in[4];

    char* ws = (char*)d_ws;
    u32* scale_bits = (u32*)ws;
    char* q8 = ws + 1024;
    char* kp8 = q8 + BB * NQ * 32;                 // 256 KB
    float* qf = (float*)(ws + 1024 + 768 * 1024);  // 1 MB
    float* kf = qf + BB * NQ * 32;                 // 2 MB
    int* out = (int*)d_out;

    (void)hipMemsetAsync(scale_bits, 0, 64, stream);

    const size_t need = 1024 + 768 * 1024 + 3 * 1024 * 1024;
    const int nblocks = (BB * (NQ + NK)) / 16 * 2;  // 3072
    const int total_elems = BB * (NQ + NK) * 32;    // 786432
    if (ws_size >= need) {
        proj_absmax_cached_kernel<<<nblocks, 256, 0, stream>>>(query, key, Wq, Wk,
                                                               scale_bits, qf, kf);
        quant_cached_kernel<<<total_elems / 256, 256, 0, stream>>>(qf, kf, scale_bits, q8, kp8);
    } else {
        proj_absmax_kernel<<<nblocks, 256, 0, stream>>>(query, key, Wq, Wk, scale_bits);
        proj_quant_kernel<<<nblocks, 256, 0, stream>>>(query, key, Wq, Wk, scale_bits, q8, kp8);
    }
    score_topk_kernel<<<(BB * NQ) / RPB, BLK, 0, stream>>>(q8, kp8, scale_bits, ow, out);
}

// Round 25
// 207.796 us; speedup vs baseline: 3.4298x; 1.0722x over previous
//
#include <hip/hip_runtime.h>
#include <stdint.h>

#define BB 2
#define NQ 4096
#define NK 8192
#define DD 512
#define HH 4
#define TOPK 64
#define CAP 256
#define RPB 2        // rows per score block
#define BLK 1024     // threads per score block (16 waves)
#define HPAD 1088    // 1024 bins + bin>>4 padding
#define SENT 0xFFFFFFFFu
#define ZBOUND 0x80000000FFFFFFFFull  // max key a nonpositive score can have

typedef unsigned int u32;
typedef unsigned long long u64;

#if defined(__has_builtin)
#if __has_builtin(__builtin_amdgcn_sdot4)
#define HAVE_SDOT4 1
#endif
#endif

// Exact int8x4 dot (int32 accumulate). PROVEN path (rounds 13-23 passed with
// this); raw `v_dot4_i32_i8` asm is WRONG on gfx950 (round 24: absmax 8186).
__device__ __forceinline__ int dot4i8(u32 a, u32 b, int acc) {
#ifdef HAVE_SDOT4
    return __builtin_amdgcn_sdot4((int)a, (int)b, acc, false);
#else
    acc += (int)(signed char)(a & 0xFF) * (int)(signed char)(b & 0xFF);
    acc += (int)(signed char)((a >> 8) & 0xFF) * (int)(signed char)((b >> 8) & 0xFF);
    acc += (int)(signed char)((a >> 16) & 0xFF) * (int)(signed char)((b >> 16) & 0xFF);
    acc += (int)(signed char)((a >> 24) & 0xFF) * (int)(signed char)((b >> 24) & 0xFF);
    return acc;
#endif
}

// ---- GOLDEN accumulation order (verified bit-exact, round 13): 2-accumulator
// interleaved FMA chains (even/odd within each float4), one combining add.

#define PROJ_BODY(EMIT)                                                          \
    __shared__ float4 xs[16][128];                                               \
    __shared__ float4 wl[128][16];                                               \
    const int nqrows = BB * NQ;                                                  \
    int blk = blockIdx.x;                                                        \
    int half = blk & 1;                                                          \
    int row0 = (blk >> 1) << 4;                                                  \
    int type = (row0 >= nqrows);                                                 \
    int trow0 = type ? row0 - nqrows : row0;                                     \
    int b = type ? (trow0 >> 13) : (trow0 >> 12);                                \
    const float* X = type ? key : query;                                         \
    const float* W = type ? Wk : Wq;                                             \
    const int t = threadIdx.x;                                                   \
    {                                                                            \
        const float4* xg = (const float4*)(X + (size_t)trow0 * DD);              \
        float4* xsf = &xs[0][0];                                                 \
        for (int i = t; i < 2048; i += 256) xsf[i] = xg[i];                      \
        const float4* wg = (const float4*)W;                                     \
        for (int i = t; i < 2048; i += 256) {                                    \
            int oo = i & 15, jj = i >> 4;                                        \
            wl[jj][oo] = wg[(size_t)(half * 16 + oo) * 128 + jj];                \
        }                                                                        \
    }                                                                            \
    __syncthreads();                                                             \
    int o16 = t & 15, lr = t >> 4;                                               \
    int o = half * 16 + o16;                                                     \
    int h = o >> 3;                                                              \
    int trow = trow0 + lr;                                                       \
    float acc0 = 0.f, acc1 = 0.f;                                                \
    _Pragma("unroll 8")                                                          \
    for (int j = 0; j < 128; ++j) {                                              \
        float4 a = xs[lr][j];                                                    \
        float4 bb = wl[j][o16];                                                  \
        acc0 = fmaf(a.x, bb.x, acc0);                                            \
        acc1 = fmaf(a.y, bb.y, acc1);                                            \
        acc0 = fmaf(a.z, bb.z, acc0);                                            \
        acc1 = fmaf(a.w, bb.w, acc1);                                            \
    }                                                                            \
    float v = acc0 + acc1;                                                       \
    EMIT

__global__ __launch_bounds__(256, 2) void proj_absmax_cached_kernel(
        const float* __restrict__ query, const float* __restrict__ key,
        const float* __restrict__ Wq, const float* __restrict__ Wk,
        u32* __restrict__ scale_bits,
        float* __restrict__ qf, float* __restrict__ kf) {
#pragma clang fp contract(off)
    __shared__ u32 lmax[4];
    if (threadIdx.x < 4) lmax[threadIdx.x] = 0u;
    PROJ_BODY(
        (type ? kf : qf)[(size_t)trow * 32 + o] = v;
        u32 bits = __float_as_uint(fabsf(v));
        __syncthreads();
        atomicMax(&lmax[h], bits);
        __syncthreads();
        if (threadIdx.x < 4 && lmax[threadIdx.x])
            atomicMax(&scale_bits[type * 8 + b * 4 + threadIdx.x], lmax[threadIdx.x]);
    )
}

__global__ __launch_bounds__(256, 2) void proj_absmax_kernel(
        const float* __restrict__ query, const float* __restrict__ key,
        const float* __restrict__ Wq, const float* __restrict__ Wk,
        u32* __restrict__ scale_bits) {
#pragma clang fp contract(off)
    __shared__ u32 lmax[4];
    if (threadIdx.x < 4) lmax[threadIdx.x] = 0u;
    PROJ_BODY(
        u32 bits = __float_as_uint(fabsf(v));
        __syncthreads();
        atomicMax(&lmax[h], bits);
        __syncthreads();
        if (threadIdx.x < 4 && lmax[threadIdx.x])
            atomicMax(&scale_bits[type * 8 + b * 4 + threadIdx.x], lmax[threadIdx.x]);
    )
}

__global__ __launch_bounds__(256) void quant_cached_kernel(
        const float* __restrict__ qf, const float* __restrict__ kf,
        const u32* __restrict__ scale_bits,
        char* __restrict__ q8, char* __restrict__ kp8) {
#pragma clang fp contract(off)
    const int nq = BB * NQ * 32;
    int gid = blockIdx.x * 256 + threadIdx.x;
    int type = (gid >= nq);
    int idx = type ? gid - nq : gid;
    int h = (idx >> 3) & 3;
    int b = type ? (idx >> 18) : (idx >> 17);
    float v = (type ? kf : qf)[idx];
    float mx = __uint_as_float(scale_bits[type * 8 + b * 4 + h]);
    float scale = (mx + 1e-6f) / 127.0f;
    float r = rintf(v / scale);
    r = fminf(fmaxf(r, -127.f), 127.f);
    (type ? kp8 : q8)[idx] = (char)(int)r;
}

__global__ __launch_bounds__(256, 2) void proj_quant_kernel(
        const float* __restrict__ query, const float* __restrict__ key,
        const float* __restrict__ Wq, const float* __restrict__ Wk,
        const u32* __restrict__ scale_bits,
        char* __restrict__ q8, char* __restrict__ kp8) {
#pragma clang fp contract(off)
    PROJ_BODY(
        float mx = __uint_as_float(scale_bits[type * 8 + b * 4 + h]);
        float scale = (mx + 1e-6f) / 127.0f;
        float r = rintf(v / scale);
        r = fminf(fmaxf(r, -127.f), 127.f);
        (type ? kp8 : q8)[(size_t)trow * 32 + o] = (char)(int)r;
    )
}

// mapped monotone score bits for row r from chunk regs c0,c1 (exact epilogue)
#define SCORE_U(r, udst) { \
    float acc = 0.f; \
    { int s = dot4i8(qa[r][0], c0.x, 0); s = dot4i8(qa[r][1], c0.y, s); \
      float sf = (float)s * tsr[r][0]; sf = fmaxf(sf, 0.f); \
      float pr = sf * wtr[0]; acc = acc + pr; } \
    { int s = dot4i8(qa[r][2], c0.z, 0); s = dot4i8(qa[r][3], c0.w, s); \
      float sf = (float)s * tsr[r][1]; sf = fmaxf(sf, 0.f); \
      float pr = sf * wtr[1]; acc = acc + pr; } \
    { int s = dot4i8(qa[r][4], c1.x, 0); s = dot4i8(qa[r][5], c1.y, s); \
      float sf = (float)s * tsr[r][2]; sf = fmaxf(sf, 0.f); \
      float pr = sf * wtr[2]; acc = acc + pr; } \
    { int s = dot4i8(qa[r][6], c1.z, 0); s = dot4i8(qa[r][7], c1.w, s); \
      float sf = (float)s * tsr[r][3]; sf = fmaxf(sf, 0.f); \
      float pr = sf * wtr[3]; acc = acc + pr; } \
    acc = acc + 0.0f; \
    u32 uu = __float_as_uint(acc); \
    udst = (uu & 0x80000000u) ? ~uu : (uu | 0x80000000u); }

// wave-local threshold selection over a filled histogram (run by wave wv==r)
#define SELECT_PASS(r, SHIFT, BINSN) do { \
    const int bpl_ = ((BINSN) >= 64) ? ((BINSN) / 64) : 1; \
    const int nact_ = ((BINSN) >= 64) ? 64 : (BINSN); \
    u32 P_ = 0u; \
    if (lane < nact_) { \
        for (int j_ = 0; j_ < bpl_; ++j_) { int bin_ = lane * bpl_ + j_; P_ += hist[r][bin_ + (bin_ >> 4)]; } } \
    u32 sI_ = P_; \
    for (int s_ = 1; s_ < 64; s_ <<= 1) { u32 o_ = __shfl_down(sI_, s_, 64); if (lane + s_ < 64) sI_ += o_; } \
    u32 sE_ = sI_ - P_; \
    u32 Gp_ = G_l[r]; \
    if (Gp_ + sE_ < TOPK && Gp_ + sI_ >= TOPK) { \
        u32 run_ = Gp_ + sE_; \
        for (int j_ = bpl_ - 1; j_ >= 0; --j_) { \
            int bin_ = lane * bpl_ + j_; u32 c_ = hist[r][bin_ + (bin_ >> 4)]; \
            if (run_ + c_ >= TOPK) { \
                T_l[r] |= ((u64)(u32)bin_) << (SHIFT); \
                G_l[r] = run_; cc_l[r] = run_ + c_; break; } \
            run_ += c_; } } \
} while (0)

// ---------- fused scores (computed once, cached) + EXACT top-64 ----------
__global__ __launch_bounds__(BLK) void score_topk_kernel(
    const char* __restrict__ q8, const char* __restrict__ kp8,
    const u32* __restrict__ scale_bits, const float* __restrict__ w,
    int* __restrict__ out) {
#pragma clang fp contract(off)
    __shared__ u32 scores[RPB][NK];   // 64 KB
    __shared__ u32 hist[RPB][HPAD];   // 8.7 KB
    __shared__ u64 cand[RPB][CAP];    // 4 KB
    __shared__ u32 cnt[RPB];
    __shared__ u64 T_l[RPB];
    __shared__ u32 G_l[RPB], cc_l[RPB];

    const int blk = blockIdx.x;
    const int row0 = blk * RPB;
    const int b = row0 >> 12;
    const int t = threadIdx.x;
    const int lane = t & 63;
    const int wv = t >> 6;

    if (t < RPB) { cnt[t] = 0u; T_l[t] = 0ull; G_l[t] = 0u; cc_l[t] = SENT; }
    for (int i = t; i < RPB * HPAD; i += BLK) (&hist[0][0])[i] = 0u;

    u32 qa[RPB][8];
    float tsr[RPB][HH], wtr[HH];
#pragma unroll
    for (int r = 0; r < RPB; ++r) {
        const u32* qr = (const u32*)(q8 + (size_t)(row0 + r) * 32);
#pragma unroll
        for (int j = 0; j < 8; ++j) qa[r][j] = qr[j];
    }
#pragma unroll
    for (int h = 0; h < HH; ++h) {
        float qsc = (__uint_as_float(scale_bits[b * 4 + h]) + 1e-6f) / 127.0f;
        float ksc = (__uint_as_float(scale_bits[8 + b * 4 + h]) + 1e-6f) / 127.0f;
        float tsv = qsc * ksc;
#pragma unroll
        for (int r = 0; r < RPB; ++r) tsr[r][h] = tsv;
        wtr[h] = w[h];
    }
    __syncthreads();

    const u32* kbase = (const u32*)(kp8 + (size_t)b * NK * 32);

    // Phase A: compute scores ONCE, cache in LDS; histogram POSITIVE scores only
    for (int i = 0; i < NK / BLK; ++i) {
        int n = t + i * BLK;
        const u32* kr = kbase + (size_t)n * 8;
        uint4 c0 = *(const uint4*)(kr);
        uint4 c1 = *(const uint4*)(kr + 4);
#define DO_ROW(r) { u32 u; SCORE_U(r, u); scores[r][n] = u; \
        if (u > 0x80000000u) { u32 bin = u >> 22; \
            atomicAdd(&hist[r][bin + (bin >> 4)], 1u); } }
        DO_ROW(0) DO_ROW(1)
#undef DO_ROW
    }
    __syncthreads();
    if (wv < RPB) SELECT_PASS(wv, 54, 1024);
    __syncthreads();

    // Exactness fallback (never taken on real data): select failed (<64
    // positives) or threshold touches the zero boundary. Redo FULL histogram.
    {
        bool f0 = (cc_l[0] == SENT) || (T_l[0] <= ZBOUND);
        bool f1 = (cc_l[1] == SENT) || (T_l[1] <= ZBOUND);
        if (f0 || f1) {
            if (t == 0) {
                if (f0) { T_l[0] = 0ull; G_l[0] = 0u; cc_l[0] = SENT; }
                if (f1) { T_l[1] = 0ull; G_l[1] = 0u; cc_l[1] = SENT; }
            }
            for (int i = t; i < RPB * HPAD; i += BLK) (&hist[0][0])[i] = 0u;
            __syncthreads();
            for (int i = 0; i < NK / BLK; ++i) {
                int n = t + i * BLK;
                if (f0) { u32 u = scores[0][n]; u32 bin = u >> 22;
                          atomicAdd(&hist[0][bin + (bin >> 4)], 1u); }
                if (f1) { u32 u = scores[1][n]; u32 bin = u >> 22;
                          atomicAdd(&hist[1][bin + (bin >> 4)], 1u); }
            }
            __syncthreads();
            if (wv == 0 && f0) SELECT_PASS(0, 54, 1024);
            if (wv == 1 && f1) SELECT_PASS(1, 54, 1024);
            __syncthreads();
        }
    }

    // refinement down the 64-bit key in 10-bit chunks (reads cached scores)
    const int shifts[6] = {44, 34, 24, 14, 4, 0};
    for (int p = 0; p < 6; ++p) {
        __syncthreads();
        if (!((cc_l[0] > CAP) || (cc_l[1] > CAP))) break;
        const int shift = shifts[p];
        const int width = (shift == 0) ? 4 : 10;
        const u32 binmask = (1u << width) - 1u;
        const u64 himask = ~0ull << (shift + width);
        for (int i = t; i < RPB * HPAD; i += BLK) (&hist[0][0])[i] = 0u;
        __syncthreads();
        for (int i = 0; i < NK / BLK; ++i) {
            int n = t + i * BLK;
            u32 lo = 0xFFFFFFFFu - (u32)n;
#define DO_ROW(r) if (cc_l[r] > CAP) { \
            u64 kk = ((u64)scores[r][n] << 32) | (u64)lo; \
            if (((kk ^ T_l[r]) & himask) == 0ull) { \
                u32 bin = (u32)(kk >> shift) & binmask; \
                atomicAdd(&hist[r][bin + (bin >> 4)], 1u); } }
            DO_ROW(0) DO_ROW(1)
#undef DO_ROW
        }
        __syncthreads();
        if (wv < RPB && cc_l[wv] > CAP) {
            if (width == 10) SELECT_PASS(wv, shift, 1024);
            else             SELECT_PASS(wv, shift, 16);
        }
    }
    __syncthreads();

    // Gather from cached scores: all keys >= T (count cc <= CAP per row)
    for (int i = 0; i < NK / BLK; ++i) {
        int n = t + i * BLK;
        u32 lo = 0xFFFFFFFFu - (u32)n;
#define DO_ROW(r) { u64 kk = ((u64)scores[r][n] << 32) | (u64)lo; \
        if (kk >= T_l[r]) { u32 pos = atomicAdd(&cnt[r], 1u); \
            if (pos < CAP) cand[r][pos] = kk; } }
        DO_ROW(0) DO_ROW(1)
#undef DO_ROW
    }
    __syncthreads();
    for (int i = t; i < RPB * CAP; i += BLK) {
        int r = i >> 8, j = i & (CAP - 1);
        if ((u32)j >= cnt[r]) cand[r][j] = 0ull;
    }

    // bitonic sort (desc), both rows simultaneously (threads 0..511 active)
    for (u32 k2 = 2; k2 <= CAP; k2 <<= 1) {
        for (u32 jj = k2 >> 1; jj > 0; jj >>= 1) {
            __syncthreads();
            if (t < RPB * CAP) {
                int r = t >> 8;
                u32 idx = (u32)(t & (CAP - 1));
                u32 partner = idx ^ jj;
                if (partner > idx) {
                    u64 a = cand[r][idx], d = cand[r][partner];
                    bool descBlock = ((idx & k2) == 0);
                    if (descBlock ? (a < d) : (a > d)) { cand[r][idx] = d; cand[r][partner] = a; }
                }
            }
        }
    }
    __syncthreads();

    if (t < RPB * TOPK) {
        int r = t >> 6, j = t & 63;
        out[(size_t)(row0 + r) * TOPK + j] = (int)(0xFFFFFFFFu - (u32)cand[r][j]);
    }
}

extern "C" void kernel_launch(void* const* d_in, const int* in_sizes, int n_in,
                              void* d_out, int out_size, void* d_ws, size_t ws_size,
                              hipStream_t stream) {
    const float* query = (const float*)d_in[0];
    const float* key = (const float*)d_in[1];
    const float* Wq = (const float*)d_in[2];
    const float* Wk = (const float*)d_in[3];
    const float* ow = (const float*)d_in[4];

    char* ws = (char*)d_ws;
    u32* scale_bits = (u32*)ws;
    char* q8 = ws + 1024;
    char* kp8 = q8 + BB * NQ * 32;                 // 256 KB
    float* qf = (float*)(ws + 1024 + 768 * 1024);  // 1 MB
    float* kf = qf + BB * NQ * 32;                 // 2 MB
    int* out = (int*)d_out;

    (void)hipMemsetAsync(scale_bits, 0, 64, stream);

    const size_t need = 1024 + 768 * 1024 + 3 * 1024 * 1024;
    const int nblocks = (BB * (NQ + NK)) / 16 * 2;  // 3072
    const int total_elems = BB * (NQ + NK) * 32;    // 786432
    if (ws_size >= need) {
        proj_absmax_cached_kernel<<<nblocks, 256, 0, stream>>>(query, key, Wq, Wk,
                                                               scale_bits, qf, kf);
        quant_cached_kernel<<<total_elems / 256, 256, 0, stream>>>(qf, kf, scale_bits, q8, kp8);
    } else {
        proj_absmax_kernel<<<nblocks, 256, 0, stream>>>(query, key, Wq, Wk, scale_bits);
        proj_quant_kernel<<<nblocks, 256, 0, stream>>>(query, key, Wq, Wk, scale_bits, q8, kp8);
    }
    score_topk_kernel<<<(BB * NQ) / RPB, BLK, 0, stream>>>(q8, kp8, scale_bits, ow, out);
}